// Round 9
// baseline (285.102 us; speedup 1.0000x reference)
//
#include <hip/hip_runtime.h>
#include <hip/hip_bf16.h>

// Transformer-XL relative MHA. fp32 in/out, bf16 intermediates in d_ws.
// B=8 T=1024 D_MODEL=512 H=8 DH=64.
// R19: exact R16 (best measured: 216.5us; attn 71.9-72.7) with ONE change:
// qkv_mfma __launch_bounds__(256,2)->(256,3). qkv grid=832 blocks (3.25/CU)
// was occupancy-capped at 2/CU; live set ~132 VGPR fits the 168 cap for
// 3 waves/SIMD -> third co-resident block hides the barrier-drain stalls
// (m97 TLP regime). Structure byte-identical. R17 (in-chunk gll+drain,
// +22us) and R18 (single-barrier/direct-V, +4.7us attn despite conflicts
// 6.8e6->3.67e6) both reverted: the R16 two-barrier reg-prefetch pipeline
// beats "cleaner" low-LDS-traffic variants; residual conflicts worth <=5us
// and every route to them cost ~10us of structure. Attn is frozen.
// Rel-shift identity: bd[t,s] = q_v[t] . p[1023 - t + s].

typedef unsigned short u16;
typedef unsigned long long u64;
typedef unsigned int u32;
typedef __attribute__((ext_vector_type(8))) short bf16x8;
typedef __attribute__((ext_vector_type(8))) unsigned short ushort8v;
typedef __attribute__((ext_vector_type(4))) float floatx4;

__device__ __forceinline__ float b2f(u16 u) {
    union { unsigned int i; float f; } x; x.i = ((unsigned int)u) << 16; return x.f;
}
__device__ __forceinline__ u16 f2b(float f) {
    __hip_bfloat16 h = __float2bfloat16(f);
    return *reinterpret_cast<u16*>(&h);
}

#define MFMA16(a, b, c) __builtin_amdgcn_mfma_f32_16x16x32_bf16(a, b, c, 0, 0, 0)

// async 16B/lane global->LDS (lds base must be wave-uniform; lane i lands
// at base + i*16)
__device__ __forceinline__ void gll16(const u16* g, u16* l) {
    __builtin_amdgcn_global_load_lds(
        (const __attribute__((address_space(1))) u32*)g,
        (__attribute__((address_space(3))) u32*)l, 16, 0, 0);
}

// ---------------------------------------------------------------- prep
// [0,2048): castX ; [2048,2368): castW x5 ; [2368,4416): maskpack ;
// [4416,4928): pe-gen (bf16 sinusoid table, 2048 rows x 512)
__global__ __launch_bounds__(256) void prep_kernel(
    const float* __restrict__ X, u16* __restrict__ Xb,
    const float* __restrict__ W0, const float* __restrict__ W1,
    const float* __restrict__ W2, const float* __restrict__ W3,
    const float* __restrict__ W4, u16* __restrict__ WT,
    const int* __restrict__ mask, u64* __restrict__ Mp,
    u16* __restrict__ Peb)
{
    const int bi = blockIdx.x;
    const int tid = threadIdx.x;
    if (bi < 2048) {
        size_t i = ((size_t)bi * 256 + tid) * 8;
        float4 a = *(const float4*)&X[i];
        float4 b = *(const float4*)&X[i + 4];
        ushort8v s;
        s[0] = f2b(a.x); s[1] = f2b(a.y); s[2] = f2b(a.z); s[3] = f2b(a.w);
        s[4] = f2b(b.x); s[5] = f2b(b.y); s[6] = f2b(b.z); s[7] = f2b(b.w);
        *(ushort8v*)&Xb[i] = s;
    } else if (bi < 2368) {
        __shared__ float t[64][68];
        const int li = bi - 2048;
        const int m = li >> 6;
        const float* src = (m == 0) ? W0 : (m == 1) ? W1 : (m == 2) ? W2
                         : (m == 3) ? W3 : W4;
        u16* dst = WT + (size_t)m * 262144;
        const int sub = li & 63;
        const int k0 = ((sub >> 3) & 7) * 64, n0 = (sub & 7) * 64;
        const int r = tid >> 4, c = tid & 15;
#pragma unroll
        for (int rr = 0; rr < 64; rr += 16) {
            float4 v = *(const float4*)&src[(size_t)(k0 + r + rr) * 512 + n0 + 4 * c];
            t[r + rr][4 * c + 0] = v.x;
            t[r + rr][4 * c + 1] = v.y;
            t[r + rr][4 * c + 2] = v.z;
            t[r + rr][4 * c + 3] = v.w;
        }
        __syncthreads();
        const int nrow = tid >> 2, kc = (tid & 3) * 16;
        ushort8v s0, s1;
#pragma unroll
        for (int e = 0; e < 8; ++e) {
            s0[e] = f2b(t[kc + e][nrow]);
            s1[e] = f2b(t[kc + 8 + e][nrow]);
        }
        *(ushort8v*)&dst[(size_t)(n0 + nrow) * 512 + k0 + kc] = s0;
        *(ushort8v*)&dst[(size_t)(n0 + nrow) * 512 + k0 + kc + 8] = s1;
    } else if (bi < 4416) {
        const int lane = tid & 63, w = tid >> 6;
        const int row = (bi - 2368) * 4 + w;
#pragma unroll
        for (int j = 0; j < 16; ++j) {
            int v = mask[(size_t)row * 1024 + j * 64 + lane];
            u64 bits = __ballot(v != 0);
            if (lane == j) Mp[(size_t)row * 16 + j] = bits;
        }
    } else {
        // ---- pe-gen: row l (wave-per-row), lane covers 8 consecutive k.
        // pe[l][2i] = sin(pos*invf_i), pe[l][2i+1] = cos(...), pos=min(l,2046)-1023
        // fast trig: angle err ~1e-4 << bf16 rounding of the table.
        const int lane = tid & 63, w = tid >> 6;
        const int l = (bi - 4416) * 4 + w;             // 0..2047
        const int lc = (l > 2046) ? 2046 : l;
        const float pos = (float)(lc - 1023);
        ushort8v s;
#pragma unroll
        for (int e = 0; e < 8; ++e) {
            int k = (lane << 3) + e;
            int i = k >> 1;
            float invf = __expf(-0.035977892f * (float)i);   // ln(1e4)/256
            float ang = pos * invf;
            float v = (k & 1) ? __cosf(ang) : __sinf(ang);
            s[e] = f2b(v);
        }
        *(ushort8v*)&Peb[(size_t)l * 512 + (lane << 3)] = s;
    }
}

// ---------------------------------------------------------------- qkv+pos MFMA
// grid (64, 13): y<12 -> QKV (y: 0-3 Q, 4-7 K, 8-11 V; n0=(y&3)*128,
// m0=x*128 over xs). y==12 -> pos GEMM: m0=(x>>2)*128 over pe (M=2048),
// n0=(x&3)*128; writes P[h][l(stride2048)][d].  (R16 register-prefetch;
// R19: 3 waves/SIMD -> 3 blocks/CU TLP.)
__global__ __launch_bounds__(256, 3) void qkv_mfma(
    const u16* __restrict__ Xb, const u16* __restrict__ WqT,
    const u16* __restrict__ WkT, const u16* __restrict__ WvT,
    const u16* __restrict__ Peb, const u16* __restrict__ WposT,
    u16* __restrict__ Qb, u16* __restrict__ Kb, u16* __restrict__ Vtg,
    u16* __restrict__ Pg)
{
    __shared__ u16 Xl[128 * 40];
    __shared__ u16 Wl[128 * 40];
    const int tid = threadIdx.x;
    const int lane = tid & 63, w = tid >> 6;
    const int quad = lane >> 4, ln = lane & 15;
    const int wm = w & 1, wn = w >> 1;

    const int yy = blockIdx.y;
    int sel, m0, n0;
    const u16 *Ap, *Bp;
    if (yy < 12) {
        sel = yy >> 2; n0 = (yy & 3) * 128; m0 = blockIdx.x * 128;
        Ap = Xb; Bp = (sel == 0) ? WqT : (sel == 1) ? WkT : WvT;
    } else {
        sel = 3; m0 = (blockIdx.x >> 2) * 128; n0 = (blockIdx.x & 3) * 128;
        Ap = Peb; Bp = WposT;
    }
    const int b = (m0 >> 10) & 7, tbase = m0 & 1023;

    const int sr = tid >> 2, sg = tid & 3;

    floatx4 acc[4][4];
#pragma unroll
    for (int i = 0; i < 4; ++i)
#pragma unroll
        for (int j = 0; j < 4; ++j) acc[i][j] = (floatx4){0.f, 0.f, 0.f, 0.f};

    ushort8v xq[2], wq2[2];
#pragma unroll
    for (int it = 0; it < 2; ++it) {
        int r = sr + it * 64;
        xq[it]  = *(const ushort8v*)&Ap[(size_t)(m0 + r) * 512 + sg * 8];
        wq2[it] = *(const ushort8v*)&Bp[(size_t)(n0 + r) * 512 + sg * 8];
    }

    for (int kc = 0; kc < 512; kc += 32) {
        __syncthreads();
#pragma unroll
        for (int it = 0; it < 2; ++it) {
            int r = sr + it * 64;
            *(ushort8v*)&Xl[r * 40 + sg * 8] = xq[it];
            *(ushort8v*)&Wl[r * 40 + sg * 8] = wq2[it];
        }
        __syncthreads();
        if (kc + 32 < 512) {
#pragma unroll
            for (int it = 0; it < 2; ++it) {
                int r = sr + it * 64;
                xq[it]  = *(const ushort8v*)&Ap[(size_t)(m0 + r) * 512 + kc + 32 + sg * 8];
                wq2[it] = *(const ushort8v*)&Bp[(size_t)(n0 + r) * 512 + kc + 32 + sg * 8];
            }
        }
        bf16x8 am[4], an[4];
#pragma unroll
        for (int i = 0; i < 4; ++i)
            am[i] = *(bf16x8*)&Xl[(wm * 64 + i * 16 + ln) * 40 + quad * 8];
#pragma unroll
        for (int j = 0; j < 4; ++j)
            an[j] = *(bf16x8*)&Wl[(wn * 64 + j * 16 + ln) * 40 + quad * 8];
        if (sel != 2) {
#pragma unroll
            for (int i = 0; i < 4; ++i)
#pragma unroll
                for (int j = 0; j < 4; ++j)
                    acc[i][j] = MFMA16(an[j], am[i], acc[i][j]);
        } else {
#pragma unroll
            for (int i = 0; i < 4; ++i)
#pragma unroll
                for (int j = 0; j < 4; ++j)
                    acc[i][j] = MFMA16(am[i], an[j], acc[i][j]);
        }
    }
    if (sel < 2) {
        u16* dst = (sel == 0) ? Qb : Kb;
#pragma unroll
        for (int i = 0; i < 4; ++i) {
            int t = tbase + wm * 64 + i * 16 + ln;
#pragma unroll
            for (int j = 0; j < 4; ++j) {
                int n = n0 + wn * 64 + j * 16 + quad * 4;
                int h = n >> 6, d = n & 63;
                ushort4 s;
                s.x = f2b(acc[i][j][0]); s.y = f2b(acc[i][j][1]);
                s.z = f2b(acc[i][j][2]); s.w = f2b(acc[i][j][3]);
                *(ushort4*)&dst[(((size_t)b * 8 + h) * 1024 + t) * 64 + d] = s;
            }
        }
    } else if (sel == 2) {
#pragma unroll
        for (int i = 0; i < 4; ++i) {
            int t4 = tbase + wm * 64 + i * 16 + quad * 4;
#pragma unroll
            for (int j = 0; j < 4; ++j) {
                int n = n0 + wn * 64 + j * 16 + ln;
                int h = n >> 6, d = n & 63;
                ushort4 s;
                s.x = f2b(acc[i][j][0]); s.y = f2b(acc[i][j][1]);
                s.z = f2b(acc[i][j][2]); s.w = f2b(acc[i][j][3]);
                *(ushort4*)&Vtg[(((size_t)b * 8 + h) * 64 + d) * 1024 + t4] = s;
            }
        }
    } else {
        // pos: P[(h*2048 + l)*64 + d]
#pragma unroll
        for (int i = 0; i < 4; ++i) {
            int l = m0 + wm * 64 + i * 16 + ln;
#pragma unroll
            for (int j = 0; j < 4; ++j) {
                int n = n0 + wn * 64 + j * 16 + quad * 4;
                int h = n >> 6, d = n & 63;
                ushort4 s;
                s.x = f2b(acc[i][j][0]); s.y = f2b(acc[i][j][1]);
                s.z = f2b(acc[i][j][2]); s.w = f2b(acc[i][j][3]);
                *(ushort4*)&Pg[(((size_t)h << 11) + l) * 64 + d] = s;
            }
        }
    }
}

// ---------------------------------------------------------------- attention
// q-bias add with the 0.125 softmax scale folded in (pow2 => scores
// bit-identical to post-scaling).
__device__ __forceinline__ bf16x8 addbias(bf16x8 q, const float* __restrict__ bias) {
    float4 a = *(const float4*)&bias[0];
    float4 b = *(const float4*)&bias[4];
    bf16x8 r;
    r[0] = (short)f2b(0.125f * (b2f((u16)q[0]) + a.x));
    r[1] = (short)f2b(0.125f * (b2f((u16)q[1]) + a.y));
    r[2] = (short)f2b(0.125f * (b2f((u16)q[2]) + a.z));
    r[3] = (short)f2b(0.125f * (b2f((u16)q[3]) + a.w));
    r[4] = (short)f2b(0.125f * (b2f((u16)q[4]) + b.x));
    r[5] = (short)f2b(0.125f * (b2f((u16)q[5]) + b.y));
    r[6] = (short)f2b(0.125f * (b2f((u16)q[6]) + b.z));
    r[7] = (short)f2b(0.125f * (b2f((u16)q[7]) + b.w));
    return r;
}

// Block = (b, h, 128 q-rows) = 4 waves x 2 sets x 16 rows. S-chunks of 64.
// Pb = 256-row ring (slot = l&255), staged 64 rows/chunk via gll16 with
// source-side XOR swizzle; read slot = quad ^ (rb&7). K/V: register
// prefetch -> stride-72 LDS (R13-proven). gw stride 84 floats.
// setprio(1) wraps the MFMA clusters (bd+ac, PV) -- register-neutral.
__global__ __launch_bounds__(256, 2) void attn_mfma(
    const u16* __restrict__ Qb,
    const u16* __restrict__ Kb, const u16* __restrict__ Vtg,
    const u16* __restrict__ P, const u64* __restrict__ Mp,
    const float* __restrict__ ub, const float* __restrict__ vb,
    u16* __restrict__ Z)
{
    __shared__ u16 Klds[64 * 72];
    __shared__ u16 Vtlds[64 * 72];
    __shared__ u16 Pb[256 * 64];
    __shared__ __align__(16) char WaveBuf[4][16 * 84 * 4];

    const int tid  = threadIdx.x;
    const int lane = tid & 63;
    const int w    = tid >> 6;
    const int quad = lane >> 4;
    const int ln   = lane & 15;

    const int bid = blockIdx.x;                    // 512 blocks
    const int xg  = bid & 7;
    const int idx = bid >> 3;
    const int bh_i = xg * 8 + (idx >> 3);
    const int t0 = (idx & 7) << 7;
    const int h  = bh_i & 7;
    const int b  = bh_i >> 3;
    const size_t bh  = (size_t)bh_i * 1024;
    const size_t bhd = (size_t)bh_i * 64;
    const int lbase0 = 896 - t0;                   // P band base for chunk 0
    size_t mprow[2];
    mprow[0] = ((size_t)b * 1024 + t0 + 16 * w + ln) * 16;
    mprow[1] = ((size_t)b * 1024 + t0 + 64 + 16 * w + ln) * 16;

    bf16x8 qu0[2], qu1[2], qv0[2], qv1[2];
#pragma unroll
    for (int c = 0; c < 2; ++c) {
        const size_t qoff = (bh + t0 + 64 * c + 16 * w + ln) * 64;
        bf16x8 q0 = *(const bf16x8*)&Qb[qoff + quad * 8];
        bf16x8 q1 = *(const bf16x8*)&Qb[qoff + 32 + quad * 8];
        qu0[c] = addbias(q0, &ub[h * 64 + quad * 8]);
        qu1[c] = addbias(q1, &ub[h * 64 + 32 + quad * 8]);
        qv0[c] = addbias(q0, &vb[h * 64 + quad * 8]);
        qv1[c] = addbias(q1, &vb[h * 64 + 32 + quad * 8]);
    }

    floatx4 O[2][4];
#pragma unroll
    for (int c = 0; c < 2; ++c)
#pragma unroll
        for (int dt = 0; dt < 4; ++dt) O[c][dt] = (floatx4){0.f, 0.f, 0.f, 0.f};
    float m_run[2] = {-3.0e38f, -3.0e38f}, l_run[2] = {0.f, 0.f};

    float* gw = (float*)&WaveBuf[w][0];
    u16*  pw  = (u16*)&WaveBuf[w][0];

    const int str = tid >> 3, stg = tid & 7;
    const int g8 = lane >> 3, s8 = lane & 7;       // gll source lane decomp
    const int pcol = ((s8 ^ g8) << 3);             // source-side XOR col
    ushort8v kq[2], vq[2];
    u64 bc0, bc1;

    // ---- prologue: P ring rows [lbase0, lbase0+192) via gll; K/V chunk 0;
    // mask bits chunk 0. All drained by the first barrier.
#pragma unroll
    for (int it = 0; it < 6; ++it) {
        int rb = lbase0 + 8 * w + 32 * it;         // 8-aligned => l&7 == lane>>3
        gll16(&P[(((size_t)h << 11) + (size_t)(rb + g8)) * 64 + pcol],
              &Pb[(rb & 255) << 6]);
    }
#pragma unroll
    for (int it = 0; it < 2; ++it) {
        int r = str + it * 32;
        kq[it] = *(const ushort8v*)&Kb[(bh + r) * 64 + stg * 8];
        vq[it] = *(const ushort8v*)&Vtg[(bhd + r) * 1024 + stg * 8];
    }
    bc0 = Mp[mprow[0]];
    bc1 = Mp[mprow[1]];

    for (int s0 = 0; s0 < 1024; s0 += 64) {
        __syncthreads();
#pragma unroll
        for (int it = 0; it < 2; ++it) {
            int r = str + it * 32;
            *(ushort8v*)&Klds[r * 72 + stg * 8] = kq[it];
            *(ushort8v*)&Vtlds[r * 72 + stg * 8] = vq[it];
        }
        __syncthreads();

        const int lb8 = (lbase0 + s0) & 255;
        u64 nb0 = 0, nb1 = 0;
        if (s0 + 64 < 1024) {
            // K/V register prefetch for next chunk
#pragma unroll
            for (int it = 0; it < 2; ++it) {
                int r = str + it * 32;
                kq[it] = *(const ushort8v*)&Kb[(bh + s0 + 64 + r) * 64 + stg * 8];
                vq[it] = *(const ushort8v*)&Vtg[(bhd + r) * 1024 + s0 + 64 + stg * 8];
            }
            // P ring: stage the 64 rows chunk i+1 adds: [lbase+192, lbase+256)
            const int lst = lbase0 + s0 + 192;
#pragma unroll
            for (int it = 0; it < 2; ++it) {
                int rb = lst + 8 * w + 32 * it;
                gll16(&P[(((size_t)h << 11) + (size_t)(rb + g8)) * 64 + pcol],
                      &Pb[(rb & 255) << 6]);
            }
            nb0 = Mp[mprow[0] + (s0 >> 6) + 1];
            nb1 = Mp[mprow[1] + (s0 >> 6) + 1];
        }

        bf16x8 vf0[4], vf1[4];
#pragma unroll
        for (int dt = 0; dt < 4; ++dt) {
            int vr = dt * 16 + ln;
            vf0[dt] = *(bf16x8*)&Vtlds[vr * 72 + quad * 8];
            vf1[dt] = *(bf16x8*)&Vtlds[vr * 72 + 32 + quad * 8];
        }

#pragma unroll
        for (int c = 0; c < 2; ++c) {
            const u64 bits = (c == 0) ? bc0 : bc1;
            const int rb0 = 112 - 64 * c - 16 * w;
            __builtin_amdgcn_s_setprio(1);
#pragma unroll
            for (int jt = 0; jt < 5; ++jt) {
                int rb = rb0 + jt * 16 + ln;
                int prow = ((lb8 + rb) & 255) << 6;
                bf16x8 a0 = *(bf16x8*)&Pb[prow + ((quad ^ (rb & 7)) << 3)];
                bf16x8 a1 = *(bf16x8*)&Pb[prow + (((4 + quad) ^ (rb & 7)) << 3)];
                floatx4 g = {0.f, 0.f, 0.f, 0.f};
                g = MFMA16(a0, qv0[c], g);
                g = MFMA16(a1, qv1[c], g);
                *(floatx4*)&gw[ln * 84 + jt * 16 + quad * 4] = g;
            }
            floatx4 cac[4];
#pragma unroll
            for (int st = 0; st < 4; ++st) {
                int kr = st * 16 + ln;
                bf16x8 a0 = *(bf16x8*)&Klds[kr * 72 + quad * 8];
                bf16x8 a1 = *(bf16x8*)&Klds[kr * 72 + 32 + quad * 8];
                floatx4 cc = {0.f, 0.f, 0.f, 0.f};
                cc = MFMA16(a0, qu0[c], cc);
                cc = MFMA16(a1, qu1[c], cc);
                cac[st] = cc;
            }
            __builtin_amdgcn_s_setprio(0);
            float sc[4][4];
            float cmax = -3.0e38f;
#pragma unroll
            for (int st = 0; st < 4; ++st) {
                int j0 = st * 16 + quad * 4 + 15 - ln;
#pragma unroll
                for (int r = 0; r < 4; ++r) {
                    float v = cac[st][r] + gw[ln * 84 + j0 + r];
                    int ss = st * 16 + quad * 4 + r;
                    v = ((bits >> ss) & 1ull) ? v : -1.0e30f;
                    sc[st][r] = v;
                    cmax = fmaxf(cmax, v);
                }
            }
            cmax = fmaxf(cmax, __shfl_xor(cmax, 16));
            cmax = fmaxf(cmax, __shfl_xor(cmax, 32));
            float m_new = fmaxf(m_run[c], cmax);
            float alpha = __expf(m_run[c] - m_new);
            float psum = 0.f;
#pragma unroll
            for (int st = 0; st < 4; ++st) {
                float p0 = __expf(sc[st][0] - m_new);
                float p1 = __expf(sc[st][1] - m_new);
                float p2 = __expf(sc[st][2] - m_new);
                float p3 = __expf(sc[st][3] - m_new);
                psum += (p0 + p1) + (p2 + p3);
                ushort4 pk;
                pk.x = f2b(p0); pk.y = f2b(p1); pk.z = f2b(p2); pk.w = f2b(p3);
                *(ushort4*)&pw[ln * 72 + st * 16 + quad * 4] = pk;
            }
            psum += __shfl_xor(psum, 16);
            psum += __shfl_xor(psum, 32);
            l_run[c] = l_run[c] * alpha + psum;
            m_run[c] = m_new;
            float a0s = __shfl(alpha, quad * 4 + 0);
            float a1s = __shfl(alpha, quad * 4 + 1);
            float a2s = __shfl(alpha, quad * 4 + 2);
            float a3s = __shfl(alpha, quad * 4 + 3);
#pragma unroll
            for (int dt = 0; dt < 4; ++dt) {
                O[c][dt][0] *= a0s; O[c][dt][1] *= a1s;
                O[c][dt][2] *= a2s; O[c][dt][3] *= a3s;
            }
            bf16x8 pa0 = *(bf16x8*)&pw[ln * 72 + quad * 8];
            bf16x8 pa1 = *(bf16x8*)&pw[ln * 72 + 32 + quad * 8];
            __builtin_amdgcn_s_setprio(1);
#pragma unroll
            for (int dt = 0; dt < 4; ++dt) {
                O[c][dt] = MFMA16(pa0, vf0[dt], O[c][dt]);
                O[c][dt] = MFMA16(pa1, vf1[dt], O[c][dt]);
            }
            __builtin_amdgcn_s_setprio(0);
        }
        bc0 = nb0; bc1 = nb1;
    }
#pragma unroll
    for (int c = 0; c < 2; ++c) {
        float li[4];
#pragma unroll
        for (int r = 0; r < 4; ++r) li[r] = 1.0f / __shfl(l_run[c], quad * 4 + r);
#pragma unroll
        for (int r = 0; r < 4; ++r) {
            size_t zo = ((size_t)b * 1024 + t0 + 64 * c + 16 * w + quad * 4 + r) * 512
                      + h * 64 + ln;
            Z[zo + 0]  = f2b(O[c][0][r] * li[r]);
            Z[zo + 16] = f2b(O[c][1][r] * li[r]);
            Z[zo + 32] = f2b(O[c][2][r] * li[r]);
            Z[zo + 48] = f2b(O[c][3][r] * li[r]);
        }
    }
}

// ---------------------------------------------------------------- out MFMA
__global__ __launch_bounds__(256, 2) void out_mfma(
    const u16* __restrict__ Zb, const u16* __restrict__ WoT,
    float* __restrict__ out)
{
    __shared__ u16 Xl[128 * 40];
    __shared__ u16 Wl[128 * 40];
    const int tid = threadIdx.x;
    const int lane = tid & 63, w = tid >> 6;
    const int quad = lane >> 4, ln = lane & 15;
    const int wm = w & 1, wn = w >> 1;
    const int m0 = blockIdx.x * 128;
    const int n0 = blockIdx.y * 128;
    const int sr = tid >> 2, sg = tid & 3;

    floatx4 acc[4][4];
#pragma unroll
    for (int i = 0; i < 4; ++i)
#pragma unroll
        for (int j = 0; j < 4; ++j) acc[i][j] = (floatx4){0.f, 0.f, 0.f, 0.f};

    ushort8v xq[2], wq2[2];
#pragma unroll
    for (int it = 0; it < 2; ++it) {
        int r = sr + it * 64;
        xq[it]  = *(const ushort8v*)&Zb[(size_t)(m0 + r) * 512 + sg * 8];
        wq2[it] = *(const ushort8v*)&WoT[(size_t)(n0 + r) * 512 + sg * 8];
    }

    for (int kc = 0; kc < 512; kc += 32) {
        __syncthreads();
#pragma unroll
        for (int it = 0; it < 2; ++it) {
            int r = sr + it * 64;
            *(ushort8v*)&Xl[r * 40 + sg * 8] = xq[it];
            *(ushort8v*)&Wl[r * 40 + sg * 8] = wq2[it];
        }
        __syncthreads();
        if (kc + 32 < 512) {
#pragma unroll
            for (int it = 0; it < 2; ++it) {
                int r = sr + it * 64;
                xq[it]  = *(const ushort8v*)&Zb[(size_t)(m0 + r) * 512 + kc + 32 + sg * 8];
                wq2[it] = *(const ushort8v*)&WoT[(size_t)(n0 + r) * 512 + kc + 32 + sg * 8];
            }
        }
        bf16x8 am[4], an[4];
#pragma unroll
        for (int i = 0; i < 4; ++i)
            am[i] = *(bf16x8*)&Xl[(wm * 64 + i * 16 + ln) * 40 + quad * 8];
#pragma unroll
        for (int j = 0; j < 4; ++j)
            an[j] = *(bf16x8*)&Wl[(wn * 64 + j * 16 + ln) * 40 + quad * 8];
#pragma unroll
        for (int i = 0; i < 4; ++i)
#pragma unroll
            for (int j = 0; j < 4; ++j)
                acc[i][j] = MFMA16(an[j], am[i], acc[i][j]);
    }
#pragma unroll
    for (int i = 0; i < 4; ++i) {
        int m = m0 + wm * 64 + i * 16 + ln;
#pragma unroll
        for (int j = 0; j < 4; ++j) {
            int n = n0 + wn * 64 + j * 16 + quad * 4;
            float4 s;
            s.x = acc[i][j][0]; s.y = acc[i][j][1];
            s.z = acc[i][j][2]; s.w = acc[i][j][3];
            *(float4*)&out[(size_t)m * 512 + n] = s;
        }
    }
}

// ---------------------------------------------------------------- launch
extern "C" void kernel_launch(void* const* d_in, const int* in_sizes, int n_in,
                              void* d_out, int out_size, void* d_ws, size_t ws_size,
                              hipStream_t stream) {
    const float* xs   = (const float*)d_in[0];
    const int*   mask = (const int*)d_in[1];
    const float* Wq   = (const float*)d_in[2];
    const float* Wk   = (const float*)d_in[3];
    const float* Wv   = (const float*)d_in[4];
    const float* Wpos = (const float*)d_in[5];
    const float* Wout = (const float*)d_in[6];
    const float* ub   = (const float*)d_in[7];
    const float* vb   = (const float*)d_in[8];
    float* out = (float*)d_out;

    u16* Qb  = (u16*)d_ws;                   // 4194304
    u16* Kb  = Qb + 4194304;                 // 4194304
    u16* Vtg = Kb + 4194304;                 // 4194304
    u16* Pg  = Vtg + 4194304;                // 8*2048*64 = 1048576
    u16* XZ  = Pg + 1048576;                 // 4194304 (Xb, then reused as Z)
    u16* WT  = XZ + 4194304;                 // 5*262144 = 1310720
    u16* WqT = WT;
    u16* WkT = WT + 262144;
    u16* WvT = WT + 524288;
    u16* WoT = WT + 786432;
    u16* WposT = WT + 1048576;
    u16* Peb = WT + 1310720;                 // 2048*512 = 1048576
    u64* Mp  = (u64*)(Peb + 1048576);        // 131072 u64

    prep_kernel<<<4928, 256, 0, stream>>>(xs, XZ, Wq, Wk, Wv, Wout, Wpos, WT,
                                          mask, Mp, Peb);
    qkv_mfma<<<dim3(64, 13), 256, 0, stream>>>(XZ, WqT, WkT, WvT, Peb, WposT,
                                               Qb, Kb, Vtg, Pg);
    attn_mfma<<<512, 256, 0, stream>>>(Qb, Kb, Vtg, Pg, Mp, ub, vb, XZ);
    out_mfma<<<dim3(64, 4), 256, 0, stream>>>(XZ, WoT, out);
}

// Round 10
// 218.042 us; speedup vs baseline: 1.3076x; 1.3076x over previous
//
#include <hip/hip_runtime.h>
#include <hip/hip_bf16.h>

// Transformer-XL relative MHA. fp32 in/out, bf16 intermediates in d_ws.
// B=8 T=1024 D_MODEL=512 H=8 DH=64.
// R20 = exact R16 restore (measured best: 216.5us). R19's qkv
// launch_bounds(256,3) forced VGPR 120->84 (unified VGPR/AGPR budget at
// 3 waves/SIMD is far below the ~130 live set) -> spill, WRITE 90MB,
// qkv 103-205us. Session rule (R12/R15/R19): this kernel family lives at
// ~120 VGPR / 2 blocks/CU; every occupancy or live-set restructure
// spilled or exposed latency. Validated levers in this config:
//   attn: P-ring via global_load_lds + src-side XOR (R14), gw stride 84
//   (R12-proven conflict fix), setprio around MFMA clusters (R16, +7us),
//   0.125 scale folded into q-bias (pow2, bit-exact), K/V reg-prefetch
//   two-barrier pipeline (R13; beats 1-barrier and direct-V variants).
//   prep: __sinf/__cosf/__expf pe-gen (R16).
//   qkv/out: R10 reg-prefetch MFMA structure @ (256,2).
// Rel-shift identity: bd[t,s] = q_v[t] . p[1023 - t + s].

typedef unsigned short u16;
typedef unsigned long long u64;
typedef unsigned int u32;
typedef __attribute__((ext_vector_type(8))) short bf16x8;
typedef __attribute__((ext_vector_type(8))) unsigned short ushort8v;
typedef __attribute__((ext_vector_type(4))) float floatx4;

__device__ __forceinline__ float b2f(u16 u) {
    union { unsigned int i; float f; } x; x.i = ((unsigned int)u) << 16; return x.f;
}
__device__ __forceinline__ u16 f2b(float f) {
    __hip_bfloat16 h = __float2bfloat16(f);
    return *reinterpret_cast<u16*>(&h);
}

#define MFMA16(a, b, c) __builtin_amdgcn_mfma_f32_16x16x32_bf16(a, b, c, 0, 0, 0)

// async 16B/lane global->LDS (lds base must be wave-uniform; lane i lands
// at base + i*16)
__device__ __forceinline__ void gll16(const u16* g, u16* l) {
    __builtin_amdgcn_global_load_lds(
        (const __attribute__((address_space(1))) u32*)g,
        (__attribute__((address_space(3))) u32*)l, 16, 0, 0);
}

// ---------------------------------------------------------------- prep
// [0,2048): castX ; [2048,2368): castW x5 ; [2368,4416): maskpack ;
// [4416,4928): pe-gen (bf16 sinusoid table, 2048 rows x 512)
__global__ __launch_bounds__(256) void prep_kernel(
    const float* __restrict__ X, u16* __restrict__ Xb,
    const float* __restrict__ W0, const float* __restrict__ W1,
    const float* __restrict__ W2, const float* __restrict__ W3,
    const float* __restrict__ W4, u16* __restrict__ WT,
    const int* __restrict__ mask, u64* __restrict__ Mp,
    u16* __restrict__ Peb)
{
    const int bi = blockIdx.x;
    const int tid = threadIdx.x;
    if (bi < 2048) {
        size_t i = ((size_t)bi * 256 + tid) * 8;
        float4 a = *(const float4*)&X[i];
        float4 b = *(const float4*)&X[i + 4];
        ushort8v s;
        s[0] = f2b(a.x); s[1] = f2b(a.y); s[2] = f2b(a.z); s[3] = f2b(a.w);
        s[4] = f2b(b.x); s[5] = f2b(b.y); s[6] = f2b(b.z); s[7] = f2b(b.w);
        *(ushort8v*)&Xb[i] = s;
    } else if (bi < 2368) {
        __shared__ float t[64][68];
        const int li = bi - 2048;
        const int m = li >> 6;
        const float* src = (m == 0) ? W0 : (m == 1) ? W1 : (m == 2) ? W2
                         : (m == 3) ? W3 : W4;
        u16* dst = WT + (size_t)m * 262144;
        const int sub = li & 63;
        const int k0 = ((sub >> 3) & 7) * 64, n0 = (sub & 7) * 64;
        const int r = tid >> 4, c = tid & 15;
#pragma unroll
        for (int rr = 0; rr < 64; rr += 16) {
            float4 v = *(const float4*)&src[(size_t)(k0 + r + rr) * 512 + n0 + 4 * c];
            t[r + rr][4 * c + 0] = v.x;
            t[r + rr][4 * c + 1] = v.y;
            t[r + rr][4 * c + 2] = v.z;
            t[r + rr][4 * c + 3] = v.w;
        }
        __syncthreads();
        const int nrow = tid >> 2, kc = (tid & 3) * 16;
        ushort8v s0, s1;
#pragma unroll
        for (int e = 0; e < 8; ++e) {
            s0[e] = f2b(t[kc + e][nrow]);
            s1[e] = f2b(t[kc + 8 + e][nrow]);
        }
        *(ushort8v*)&dst[(size_t)(n0 + nrow) * 512 + k0 + kc] = s0;
        *(ushort8v*)&dst[(size_t)(n0 + nrow) * 512 + k0 + kc + 8] = s1;
    } else if (bi < 4416) {
        const int lane = tid & 63, w = tid >> 6;
        const int row = (bi - 2368) * 4 + w;
#pragma unroll
        for (int j = 0; j < 16; ++j) {
            int v = mask[(size_t)row * 1024 + j * 64 + lane];
            u64 bits = __ballot(v != 0);
            if (lane == j) Mp[(size_t)row * 16 + j] = bits;
        }
    } else {
        // ---- pe-gen: row l (wave-per-row), lane covers 8 consecutive k.
        // pe[l][2i] = sin(pos*invf_i), pe[l][2i+1] = cos(...), pos=min(l,2046)-1023
        // fast trig: angle err ~1e-4 << bf16 rounding of the table.
        const int lane = tid & 63, w = tid >> 6;
        const int l = (bi - 4416) * 4 + w;             // 0..2047
        const int lc = (l > 2046) ? 2046 : l;
        const float pos = (float)(lc - 1023);
        ushort8v s;
#pragma unroll
        for (int e = 0; e < 8; ++e) {
            int k = (lane << 3) + e;
            int i = k >> 1;
            float invf = __expf(-0.035977892f * (float)i);   // ln(1e4)/256
            float ang = pos * invf;
            float v = (k & 1) ? __cosf(ang) : __sinf(ang);
            s[e] = f2b(v);
        }
        *(ushort8v*)&Peb[(size_t)l * 512 + (lane << 3)] = s;
    }
}

// ---------------------------------------------------------------- qkv+pos MFMA
// grid (64, 13): y<12 -> QKV (y: 0-3 Q, 4-7 K, 8-11 V; n0=(y&3)*128,
// m0=x*128 over xs). y==12 -> pos GEMM: m0=(x>>2)*128 over pe (M=2048),
// n0=(x&3)*128; writes P[h][l(stride2048)][d].  (R16 register-prefetch,
// (256,2): ~120 VGPR, no spill -- (256,3) forced 84 VGPR + 90MB scratch.)
__global__ __launch_bounds__(256, 2) void qkv_mfma(
    const u16* __restrict__ Xb, const u16* __restrict__ WqT,
    const u16* __restrict__ WkT, const u16* __restrict__ WvT,
    const u16* __restrict__ Peb, const u16* __restrict__ WposT,
    u16* __restrict__ Qb, u16* __restrict__ Kb, u16* __restrict__ Vtg,
    u16* __restrict__ Pg)
{
    __shared__ u16 Xl[128 * 40];
    __shared__ u16 Wl[128 * 40];
    const int tid = threadIdx.x;
    const int lane = tid & 63, w = tid >> 6;
    const int quad = lane >> 4, ln = lane & 15;
    const int wm = w & 1, wn = w >> 1;

    const int yy = blockIdx.y;
    int sel, m0, n0;
    const u16 *Ap, *Bp;
    if (yy < 12) {
        sel = yy >> 2; n0 = (yy & 3) * 128; m0 = blockIdx.x * 128;
        Ap = Xb; Bp = (sel == 0) ? WqT : (sel == 1) ? WkT : WvT;
    } else {
        sel = 3; m0 = (blockIdx.x >> 2) * 128; n0 = (blockIdx.x & 3) * 128;
        Ap = Peb; Bp = WposT;
    }
    const int b = (m0 >> 10) & 7, tbase = m0 & 1023;

    const int sr = tid >> 2, sg = tid & 3;

    floatx4 acc[4][4];
#pragma unroll
    for (int i = 0; i < 4; ++i)
#pragma unroll
        for (int j = 0; j < 4; ++j) acc[i][j] = (floatx4){0.f, 0.f, 0.f, 0.f};

    ushort8v xq[2], wq2[2];
#pragma unroll
    for (int it = 0; it < 2; ++it) {
        int r = sr + it * 64;
        xq[it]  = *(const ushort8v*)&Ap[(size_t)(m0 + r) * 512 + sg * 8];
        wq2[it] = *(const ushort8v*)&Bp[(size_t)(n0 + r) * 512 + sg * 8];
    }

    for (int kc = 0; kc < 512; kc += 32) {
        __syncthreads();
#pragma unroll
        for (int it = 0; it < 2; ++it) {
            int r = sr + it * 64;
            *(ushort8v*)&Xl[r * 40 + sg * 8] = xq[it];
            *(ushort8v*)&Wl[r * 40 + sg * 8] = wq2[it];
        }
        __syncthreads();
        if (kc + 32 < 512) {
#pragma unroll
            for (int it = 0; it < 2; ++it) {
                int r = sr + it * 64;
                xq[it]  = *(const ushort8v*)&Ap[(size_t)(m0 + r) * 512 + kc + 32 + sg * 8];
                wq2[it] = *(const ushort8v*)&Bp[(size_t)(n0 + r) * 512 + kc + 32 + sg * 8];
            }
        }
        bf16x8 am[4], an[4];
#pragma unroll
        for (int i = 0; i < 4; ++i)
            am[i] = *(bf16x8*)&Xl[(wm * 64 + i * 16 + ln) * 40 + quad * 8];
#pragma unroll
        for (int j = 0; j < 4; ++j)
            an[j] = *(bf16x8*)&Wl[(wn * 64 + j * 16 + ln) * 40 + quad * 8];
        if (sel != 2) {
#pragma unroll
            for (int i = 0; i < 4; ++i)
#pragma unroll
                for (int j = 0; j < 4; ++j)
                    acc[i][j] = MFMA16(an[j], am[i], acc[i][j]);
        } else {
#pragma unroll
            for (int i = 0; i < 4; ++i)
#pragma unroll
                for (int j = 0; j < 4; ++j)
                    acc[i][j] = MFMA16(am[i], an[j], acc[i][j]);
        }
    }
    if (sel < 2) {
        u16* dst = (sel == 0) ? Qb : Kb;
#pragma unroll
        for (int i = 0; i < 4; ++i) {
            int t = tbase + wm * 64 + i * 16 + ln;
#pragma unroll
            for (int j = 0; j < 4; ++j) {
                int n = n0 + wn * 64 + j * 16 + quad * 4;
                int h = n >> 6, d = n & 63;
                ushort4 s;
                s.x = f2b(acc[i][j][0]); s.y = f2b(acc[i][j][1]);
                s.z = f2b(acc[i][j][2]); s.w = f2b(acc[i][j][3]);
                *(ushort4*)&dst[(((size_t)b * 8 + h) * 1024 + t) * 64 + d] = s;
            }
        }
    } else if (sel == 2) {
#pragma unroll
        for (int i = 0; i < 4; ++i) {
            int t4 = tbase + wm * 64 + i * 16 + quad * 4;
#pragma unroll
            for (int j = 0; j < 4; ++j) {
                int n = n0 + wn * 64 + j * 16 + ln;
                int h = n >> 6, d = n & 63;
                ushort4 s;
                s.x = f2b(acc[i][j][0]); s.y = f2b(acc[i][j][1]);
                s.z = f2b(acc[i][j][2]); s.w = f2b(acc[i][j][3]);
                *(ushort4*)&Vtg[(((size_t)b * 8 + h) * 64 + d) * 1024 + t4] = s;
            }
        }
    } else {
        // pos: P[(h*2048 + l)*64 + d]
#pragma unroll
        for (int i = 0; i < 4; ++i) {
            int l = m0 + wm * 64 + i * 16 + ln;
#pragma unroll
            for (int j = 0; j < 4; ++j) {
                int n = n0 + wn * 64 + j * 16 + quad * 4;
                int h = n >> 6, d = n & 63;
                ushort4 s;
                s.x = f2b(acc[i][j][0]); s.y = f2b(acc[i][j][1]);
                s.z = f2b(acc[i][j][2]); s.w = f2b(acc[i][j][3]);
                *(ushort4*)&Pg[(((size_t)h << 11) + l) * 64 + d] = s;
            }
        }
    }
}

// ---------------------------------------------------------------- attention
// q-bias add with the 0.125 softmax scale folded in (pow2 => scores
// bit-identical to post-scaling).
__device__ __forceinline__ bf16x8 addbias(bf16x8 q, const float* __restrict__ bias) {
    float4 a = *(const float4*)&bias[0];
    float4 b = *(const float4*)&bias[4];
    bf16x8 r;
    r[0] = (short)f2b(0.125f * (b2f((u16)q[0]) + a.x));
    r[1] = (short)f2b(0.125f * (b2f((u16)q[1]) + a.y));
    r[2] = (short)f2b(0.125f * (b2f((u16)q[2]) + a.z));
    r[3] = (short)f2b(0.125f * (b2f((u16)q[3]) + a.w));
    r[4] = (short)f2b(0.125f * (b2f((u16)q[4]) + b.x));
    r[5] = (short)f2b(0.125f * (b2f((u16)q[5]) + b.y));
    r[6] = (short)f2b(0.125f * (b2f((u16)q[6]) + b.z));
    r[7] = (short)f2b(0.125f * (b2f((u16)q[7]) + b.w));
    return r;
}

// Block = (b, h, 128 q-rows) = 4 waves x 2 sets x 16 rows. S-chunks of 64.
// Pb = 256-row ring (slot = l&255), staged 64 rows/chunk via gll16 with
// source-side XOR swizzle; read slot = quad ^ (rb&7). K/V: register
// prefetch -> stride-72 LDS (R13-proven). gw stride 84 floats.
// setprio(1) wraps the MFMA clusters (bd+ac, PV) -- register-neutral.
__global__ __launch_bounds__(256, 2) void attn_mfma(
    const u16* __restrict__ Qb,
    const u16* __restrict__ Kb, const u16* __restrict__ Vtg,
    const u16* __restrict__ P, const u64* __restrict__ Mp,
    const float* __restrict__ ub, const float* __restrict__ vb,
    u16* __restrict__ Z)
{
    __shared__ u16 Klds[64 * 72];
    __shared__ u16 Vtlds[64 * 72];
    __shared__ u16 Pb[256 * 64];
    __shared__ __align__(16) char WaveBuf[4][16 * 84 * 4];

    const int tid  = threadIdx.x;
    const int lane = tid & 63;
    const int w    = tid >> 6;
    const int quad = lane >> 4;
    const int ln   = lane & 15;

    const int bid = blockIdx.x;                    // 512 blocks
    const int xg  = bid & 7;
    const int idx = bid >> 3;
    const int bh_i = xg * 8 + (idx >> 3);
    const int t0 = (idx & 7) << 7;
    const int h  = bh_i & 7;
    const int b  = bh_i >> 3;
    const size_t bh  = (size_t)bh_i * 1024;
    const size_t bhd = (size_t)bh_i * 64;
    const int lbase0 = 896 - t0;                   // P band base for chunk 0
    size_t mprow[2];
    mprow[0] = ((size_t)b * 1024 + t0 + 16 * w + ln) * 16;
    mprow[1] = ((size_t)b * 1024 + t0 + 64 + 16 * w + ln) * 16;

    bf16x8 qu0[2], qu1[2], qv0[2], qv1[2];
#pragma unroll
    for (int c = 0; c < 2; ++c) {
        const size_t qoff = (bh + t0 + 64 * c + 16 * w + ln) * 64;
        bf16x8 q0 = *(const bf16x8*)&Qb[qoff + quad * 8];
        bf16x8 q1 = *(const bf16x8*)&Qb[qoff + 32 + quad * 8];
        qu0[c] = addbias(q0, &ub[h * 64 + quad * 8]);
        qu1[c] = addbias(q1, &ub[h * 64 + 32 + quad * 8]);
        qv0[c] = addbias(q0, &vb[h * 64 + quad * 8]);
        qv1[c] = addbias(q1, &vb[h * 64 + 32 + quad * 8]);
    }

    floatx4 O[2][4];
#pragma unroll
    for (int c = 0; c < 2; ++c)
#pragma unroll
        for (int dt = 0; dt < 4; ++dt) O[c][dt] = (floatx4){0.f, 0.f, 0.f, 0.f};
    float m_run[2] = {-3.0e38f, -3.0e38f}, l_run[2] = {0.f, 0.f};

    float* gw = (float*)&WaveBuf[w][0];
    u16*  pw  = (u16*)&WaveBuf[w][0];

    const int str = tid >> 3, stg = tid & 7;
    const int g8 = lane >> 3, s8 = lane & 7;       // gll source lane decomp
    const int pcol = ((s8 ^ g8) << 3);             // source-side XOR col
    ushort8v kq[2], vq[2];
    u64 bc0, bc1;

    // ---- prologue: P ring rows [lbase0, lbase0+192) via gll; K/V chunk 0;
    // mask bits chunk 0. All drained by the first barrier.
#pragma unroll
    for (int it = 0; it < 6; ++it) {
        int rb = lbase0 + 8 * w + 32 * it;         // 8-aligned => l&7 == lane>>3
        gll16(&P[(((size_t)h << 11) + (size_t)(rb + g8)) * 64 + pcol],
              &Pb[(rb & 255) << 6]);
    }
#pragma unroll
    for (int it = 0; it < 2; ++it) {
        int r = str + it * 32;
        kq[it] = *(const ushort8v*)&Kb[(bh + r) * 64 + stg * 8];
        vq[it] = *(const ushort8v*)&Vtg[(bhd + r) * 1024 + stg * 8];
    }
    bc0 = Mp[mprow[0]];
    bc1 = Mp[mprow[1]];

    for (int s0 = 0; s0 < 1024; s0 += 64) {
        __syncthreads();
#pragma unroll
        for (int it = 0; it < 2; ++it) {
            int r = str + it * 32;
            *(ushort8v*)&Klds[r * 72 + stg * 8] = kq[it];
            *(ushort8v*)&Vtlds[r * 72 + stg * 8] = vq[it];
        }
        __syncthreads();

        const int lb8 = (lbase0 + s0) & 255;
        u64 nb0 = 0, nb1 = 0;
        if (s0 + 64 < 1024) {
            // K/V register prefetch for next chunk
#pragma unroll
            for (int it = 0; it < 2; ++it) {
                int r = str + it * 32;
                kq[it] = *(const ushort8v*)&Kb[(bh + s0 + 64 + r) * 64 + stg * 8];
                vq[it] = *(const ushort8v*)&Vtg[(bhd + r) * 1024 + s0 + 64 + stg * 8];
            }
            // P ring: stage the 64 rows chunk i+1 adds: [lbase+192, lbase+256)
            const int lst = lbase0 + s0 + 192;
#pragma unroll
            for (int it = 0; it < 2; ++it) {
                int rb = lst + 8 * w + 32 * it;
                gll16(&P[(((size_t)h << 11) + (size_t)(rb + g8)) * 64 + pcol],
                      &Pb[(rb & 255) << 6]);
            }
            nb0 = Mp[mprow[0] + (s0 >> 6) + 1];
            nb1 = Mp[mprow[1] + (s0 >> 6) + 1];
        }

        bf16x8 vf0[4], vf1[4];
#pragma unroll
        for (int dt = 0; dt < 4; ++dt) {
            int vr = dt * 16 + ln;
            vf0[dt] = *(bf16x8*)&Vtlds[vr * 72 + quad * 8];
            vf1[dt] = *(bf16x8*)&Vtlds[vr * 72 + 32 + quad * 8];
        }

#pragma unroll
        for (int c = 0; c < 2; ++c) {
            const u64 bits = (c == 0) ? bc0 : bc1;
            const int rb0 = 112 - 64 * c - 16 * w;
            __builtin_amdgcn_s_setprio(1);
#pragma unroll
            for (int jt = 0; jt < 5; ++jt) {
                int rb = rb0 + jt * 16 + ln;
                int prow = ((lb8 + rb) & 255) << 6;
                bf16x8 a0 = *(bf16x8*)&Pb[prow + ((quad ^ (rb & 7)) << 3)];
                bf16x8 a1 = *(bf16x8*)&Pb[prow + (((4 + quad) ^ (rb & 7)) << 3)];
                floatx4 g = {0.f, 0.f, 0.f, 0.f};
                g = MFMA16(a0, qv0[c], g);
                g = MFMA16(a1, qv1[c], g);
                *(floatx4*)&gw[ln * 84 + jt * 16 + quad * 4] = g;
            }
            floatx4 cac[4];
#pragma unroll
            for (int st = 0; st < 4; ++st) {
                int kr = st * 16 + ln;
                bf16x8 a0 = *(bf16x8*)&Klds[kr * 72 + quad * 8];
                bf16x8 a1 = *(bf16x8*)&Klds[kr * 72 + 32 + quad * 8];
                floatx4 cc = {0.f, 0.f, 0.f, 0.f};
                cc = MFMA16(a0, qu0[c], cc);
                cc = MFMA16(a1, qu1[c], cc);
                cac[st] = cc;
            }
            __builtin_amdgcn_s_setprio(0);
            float sc[4][4];
            float cmax = -3.0e38f;
#pragma unroll
            for (int st = 0; st < 4; ++st) {
                int j0 = st * 16 + quad * 4 + 15 - ln;
#pragma unroll
                for (int r = 0; r < 4; ++r) {
                    float v = cac[st][r] + gw[ln * 84 + j0 + r];
                    int ss = st * 16 + quad * 4 + r;
                    v = ((bits >> ss) & 1ull) ? v : -1.0e30f;
                    sc[st][r] = v;
                    cmax = fmaxf(cmax, v);
                }
            }
            cmax = fmaxf(cmax, __shfl_xor(cmax, 16));
            cmax = fmaxf(cmax, __shfl_xor(cmax, 32));
            float m_new = fmaxf(m_run[c], cmax);
            float alpha = __expf(m_run[c] - m_new);
            float psum = 0.f;
#pragma unroll
            for (int st = 0; st < 4; ++st) {
                float p0 = __expf(sc[st][0] - m_new);
                float p1 = __expf(sc[st][1] - m_new);
                float p2 = __expf(sc[st][2] - m_new);
                float p3 = __expf(sc[st][3] - m_new);
                psum += (p0 + p1) + (p2 + p3);
                ushort4 pk;
                pk.x = f2b(p0); pk.y = f2b(p1); pk.z = f2b(p2); pk.w = f2b(p3);
                *(ushort4*)&pw[ln * 72 + st * 16 + quad * 4] = pk;
            }
            psum += __shfl_xor(psum, 16);
            psum += __shfl_xor(psum, 32);
            l_run[c] = l_run[c] * alpha + psum;
            m_run[c] = m_new;
            float a0s = __shfl(alpha, quad * 4 + 0);
            float a1s = __shfl(alpha, quad * 4 + 1);
            float a2s = __shfl(alpha, quad * 4 + 2);
            float a3s = __shfl(alpha, quad * 4 + 3);
#pragma unroll
            for (int dt = 0; dt < 4; ++dt) {
                O[c][dt][0] *= a0s; O[c][dt][1] *= a1s;
                O[c][dt][2] *= a2s; O[c][dt][3] *= a3s;
            }
            bf16x8 pa0 = *(bf16x8*)&pw[ln * 72 + quad * 8];
            bf16x8 pa1 = *(bf16x8*)&pw[ln * 72 + 32 + quad * 8];
            __builtin_amdgcn_s_setprio(1);
#pragma unroll
            for (int dt = 0; dt < 4; ++dt) {
                O[c][dt] = MFMA16(pa0, vf0[dt], O[c][dt]);
                O[c][dt] = MFMA16(pa1, vf1[dt], O[c][dt]);
            }
            __builtin_amdgcn_s_setprio(0);
        }
        bc0 = nb0; bc1 = nb1;
    }
#pragma unroll
    for (int c = 0; c < 2; ++c) {
        float li[4];
#pragma unroll
        for (int r = 0; r < 4; ++r) li[r] = 1.0f / __shfl(l_run[c], quad * 4 + r);
#pragma unroll
        for (int r = 0; r < 4; ++r) {
            size_t zo = ((size_t)b * 1024 + t0 + 64 * c + 16 * w + quad * 4 + r) * 512
                      + h * 64 + ln;
            Z[zo + 0]  = f2b(O[c][0][r] * li[r]);
            Z[zo + 16] = f2b(O[c][1][r] * li[r]);
            Z[zo + 32] = f2b(O[c][2][r] * li[r]);
            Z[zo + 48] = f2b(O[c][3][r] * li[r]);
        }
    }
}

// ---------------------------------------------------------------- out MFMA
__global__ __launch_bounds__(256, 2) void out_mfma(
    const u16* __restrict__ Zb, const u16* __restrict__ WoT,
    float* __restrict__ out)
{
    __shared__ u16 Xl[128 * 40];
    __shared__ u16 Wl[128 * 40];
    const int tid = threadIdx.x;
    const int lane = tid & 63, w = tid >> 6;
    const int quad = lane >> 4, ln = lane & 15;
    const int wm = w & 1, wn = w >> 1;
    const int m0 = blockIdx.x * 128;
    const int n0 = blockIdx.y * 128;
    const int sr = tid >> 2, sg = tid & 3;

    floatx4 acc[4][4];
#pragma unroll
    for (int i = 0; i < 4; ++i)
#pragma unroll
        for (int j = 0; j < 4; ++j) acc[i][j] = (floatx4){0.f, 0.f, 0.f, 0.f};

    ushort8v xq[2], wq2[2];
#pragma unroll
    for (int it = 0; it < 2; ++it) {
        int r = sr + it * 64;
        xq[it]  = *(const ushort8v*)&Zb[(size_t)(m0 + r) * 512 + sg * 8];
        wq2[it] = *(const ushort8v*)&WoT[(size_t)(n0 + r) * 512 + sg * 8];
    }

    for (int kc = 0; kc < 512; kc += 32) {
        __syncthreads();
#pragma unroll
        for (int it = 0; it < 2; ++it) {
            int r = sr + it * 64;
            *(ushort8v*)&Xl[r * 40 + sg * 8] = xq[it];
            *(ushort8v*)&Wl[r * 40 + sg * 8] = wq2[it];
        }
        __syncthreads();
        if (kc + 32 < 512) {
#pragma unroll
            for (int it = 0; it < 2; ++it) {
                int r = sr + it * 64;
                xq[it]  = *(const ushort8v*)&Zb[(size_t)(m0 + r) * 512 + kc + 32 + sg * 8];
                wq2[it] = *(const ushort8v*)&WoT[(size_t)(n0 + r) * 512 + kc + 32 + sg * 8];
            }
        }
        bf16x8 am[4], an[4];
#pragma unroll
        for (int i = 0; i < 4; ++i)
            am[i] = *(bf16x8*)&Xl[(wm * 64 + i * 16 + ln) * 40 + quad * 8];
#pragma unroll
        for (int j = 0; j < 4; ++j)
            an[j] = *(bf16x8*)&Wl[(wn * 64 + j * 16 + ln) * 40 + quad * 8];
#pragma unroll
        for (int i = 0; i < 4; ++i)
#pragma unroll
            for (int j = 0; j < 4; ++j)
                acc[i][j] = MFMA16(an[j], am[i], acc[i][j]);
    }
#pragma unroll
    for (int i = 0; i < 4; ++i) {
        int m = m0 + wm * 64 + i * 16 + ln;
#pragma unroll
        for (int j = 0; j < 4; ++j) {
            int n = n0 + wn * 64 + j * 16 + quad * 4;
            float4 s;
            s.x = acc[i][j][0]; s.y = acc[i][j][1];
            s.z = acc[i][j][2]; s.w = acc[i][j][3];
            *(float4*)&out[(size_t)m * 512 + n] = s;
        }
    }
}

// ---------------------------------------------------------------- launch
extern "C" void kernel_launch(void* const* d_in, const int* in_sizes, int n_in,
                              void* d_out, int out_size, void* d_ws, size_t ws_size,
                              hipStream_t stream) {
    const float* xs   = (const float*)d_in[0];
    const int*   mask = (const int*)d_in[1];
    const float* Wq   = (const float*)d_in[2];
    const float* Wk   = (const float*)d_in[3];
    const float* Wv   = (const float*)d_in[4];
    const float* Wpos = (const float*)d_in[5];
    const float* Wout = (const float*)d_in[6];
    const float* ub   = (const float*)d_in[7];
    const float* vb   = (const float*)d_in[8];
    float* out = (float*)d_out;

    u16* Qb  = (u16*)d_ws;                   // 4194304
    u16* Kb  = Qb + 4194304;                 // 4194304
    u16* Vtg = Kb + 4194304;                 // 4194304
    u16* Pg  = Vtg + 4194304;                // 8*2048*64 = 1048576
    u16* XZ  = Pg + 1048576;                 // 4194304 (Xb, then reused as Z)
    u16* WT  = XZ + 4194304;                 // 5*262144 = 1310720
    u16* WqT = WT;
    u16* WkT = WT + 262144;
    u16* WvT = WT + 524288;
    u16* WoT = WT + 786432;
    u16* WposT = WT + 1048576;
    u16* Peb = WT + 1310720;                 // 2048*512 = 1048576
    u64* Mp  = (u64*)(Peb + 1048576);        // 131072 u64

    prep_kernel<<<4928, 256, 0, stream>>>(xs, XZ, Wq, Wk, Wv, Wout, Wpos, WT,
                                          mask, Mp, Peb);
    qkv_mfma<<<dim3(64, 13), 256, 0, stream>>>(XZ, WqT, WkT, WvT, Peb, WposT,
                                               Qb, Kb, Vtg, Pg);
    attn_mfma<<<512, 256, 0, stream>>>(Qb, Kb, Vtg, Pg, Mp, ub, vb, XZ);
    out_mfma<<<dim3(64, 4), 256, 0, stream>>>(XZ, WoT, out);
}

// Round 11
// 215.782 us; speedup vs baseline: 1.3212x; 1.0105x over previous
//
#include <hip/hip_runtime.h>
#include <hip/hip_bf16.h>

// Transformer-XL relative MHA. fp32 in/out, bf16 intermediates in d_ws.
// B=8 T=1024 D_MODEL=512 H=8 DH=64.
// R21 = R20/R16 (stable best, 216.5-218.0us) + the one untried
// register-neutral lever: s_setprio(1) around the MFMA clusters of
// qkv_mfma and out_mfma (R16 measured +7us on attn from the same
// mechanism; both GEMMs run 2 independent blocks/CU -> same role
// diversity for the CU scheduler to arbitrate). Zero structural change.
// Session rules (R12/R15/R17/R18/R19 all regressed+reverted): this
// kernel family lives at ~120 VGPR / 2 blocks/CU; reg-prefetch
// two-barrier pipelines beat gll-in-chunk and 1-barrier variants;
// conflicts are at their 6.8e6 floor (intrinsic wide-op serialization).
// Rel-shift identity: bd[t,s] = q_v[t] . p[1023 - t + s].

typedef unsigned short u16;
typedef unsigned long long u64;
typedef unsigned int u32;
typedef __attribute__((ext_vector_type(8))) short bf16x8;
typedef __attribute__((ext_vector_type(8))) unsigned short ushort8v;
typedef __attribute__((ext_vector_type(4))) float floatx4;

__device__ __forceinline__ float b2f(u16 u) {
    union { unsigned int i; float f; } x; x.i = ((unsigned int)u) << 16; return x.f;
}
__device__ __forceinline__ u16 f2b(float f) {
    __hip_bfloat16 h = __float2bfloat16(f);
    return *reinterpret_cast<u16*>(&h);
}

#define MFMA16(a, b, c) __builtin_amdgcn_mfma_f32_16x16x32_bf16(a, b, c, 0, 0, 0)

// async 16B/lane global->LDS (lds base must be wave-uniform; lane i lands
// at base + i*16)
__device__ __forceinline__ void gll16(const u16* g, u16* l) {
    __builtin_amdgcn_global_load_lds(
        (const __attribute__((address_space(1))) u32*)g,
        (__attribute__((address_space(3))) u32*)l, 16, 0, 0);
}

// ---------------------------------------------------------------- prep
// [0,2048): castX ; [2048,2368): castW x5 ; [2368,4416): maskpack ;
// [4416,4928): pe-gen (bf16 sinusoid table, 2048 rows x 512)
__global__ __launch_bounds__(256) void prep_kernel(
    const float* __restrict__ X, u16* __restrict__ Xb,
    const float* __restrict__ W0, const float* __restrict__ W1,
    const float* __restrict__ W2, const float* __restrict__ W3,
    const float* __restrict__ W4, u16* __restrict__ WT,
    const int* __restrict__ mask, u64* __restrict__ Mp,
    u16* __restrict__ Peb)
{
    const int bi = blockIdx.x;
    const int tid = threadIdx.x;
    if (bi < 2048) {
        size_t i = ((size_t)bi * 256 + tid) * 8;
        float4 a = *(const float4*)&X[i];
        float4 b = *(const float4*)&X[i + 4];
        ushort8v s;
        s[0] = f2b(a.x); s[1] = f2b(a.y); s[2] = f2b(a.z); s[3] = f2b(a.w);
        s[4] = f2b(b.x); s[5] = f2b(b.y); s[6] = f2b(b.z); s[7] = f2b(b.w);
        *(ushort8v*)&Xb[i] = s;
    } else if (bi < 2368) {
        __shared__ float t[64][68];
        const int li = bi - 2048;
        const int m = li >> 6;
        const float* src = (m == 0) ? W0 : (m == 1) ? W1 : (m == 2) ? W2
                         : (m == 3) ? W3 : W4;
        u16* dst = WT + (size_t)m * 262144;
        const int sub = li & 63;
        const int k0 = ((sub >> 3) & 7) * 64, n0 = (sub & 7) * 64;
        const int r = tid >> 4, c = tid & 15;
#pragma unroll
        for (int rr = 0; rr < 64; rr += 16) {
            float4 v = *(const float4*)&src[(size_t)(k0 + r + rr) * 512 + n0 + 4 * c];
            t[r + rr][4 * c + 0] = v.x;
            t[r + rr][4 * c + 1] = v.y;
            t[r + rr][4 * c + 2] = v.z;
            t[r + rr][4 * c + 3] = v.w;
        }
        __syncthreads();
        const int nrow = tid >> 2, kc = (tid & 3) * 16;
        ushort8v s0, s1;
#pragma unroll
        for (int e = 0; e < 8; ++e) {
            s0[e] = f2b(t[kc + e][nrow]);
            s1[e] = f2b(t[kc + 8 + e][nrow]);
        }
        *(ushort8v*)&dst[(size_t)(n0 + nrow) * 512 + k0 + kc] = s0;
        *(ushort8v*)&dst[(size_t)(n0 + nrow) * 512 + k0 + kc + 8] = s1;
    } else if (bi < 4416) {
        const int lane = tid & 63, w = tid >> 6;
        const int row = (bi - 2368) * 4 + w;
#pragma unroll
        for (int j = 0; j < 16; ++j) {
            int v = mask[(size_t)row * 1024 + j * 64 + lane];
            u64 bits = __ballot(v != 0);
            if (lane == j) Mp[(size_t)row * 16 + j] = bits;
        }
    } else {
        // ---- pe-gen: row l (wave-per-row), lane covers 8 consecutive k.
        // pe[l][2i] = sin(pos*invf_i), pe[l][2i+1] = cos(...), pos=min(l,2046)-1023
        // fast trig: angle err ~1e-4 << bf16 rounding of the table.
        const int lane = tid & 63, w = tid >> 6;
        const int l = (bi - 4416) * 4 + w;             // 0..2047
        const int lc = (l > 2046) ? 2046 : l;
        const float pos = (float)(lc - 1023);
        ushort8v s;
#pragma unroll
        for (int e = 0; e < 8; ++e) {
            int k = (lane << 3) + e;
            int i = k >> 1;
            float invf = __expf(-0.035977892f * (float)i);   // ln(1e4)/256
            float ang = pos * invf;
            float v = (k & 1) ? __cosf(ang) : __sinf(ang);
            s[e] = f2b(v);
        }
        *(ushort8v*)&Peb[(size_t)l * 512 + (lane << 3)] = s;
    }
}

// ---------------------------------------------------------------- qkv+pos MFMA
// grid (64, 13): y<12 -> QKV (y: 0-3 Q, 4-7 K, 8-11 V; n0=(y&3)*128,
// m0=x*128 over xs). y==12 -> pos GEMM: m0=(x>>2)*128 over pe (M=2048),
// n0=(x&3)*128; writes P[h][l(stride2048)][d].  (R16 register-prefetch,
// (256,2); R21: setprio(1) around fragment-read+MFMA cluster.)
__global__ __launch_bounds__(256, 2) void qkv_mfma(
    const u16* __restrict__ Xb, const u16* __restrict__ WqT,
    const u16* __restrict__ WkT, const u16* __restrict__ WvT,
    const u16* __restrict__ Peb, const u16* __restrict__ WposT,
    u16* __restrict__ Qb, u16* __restrict__ Kb, u16* __restrict__ Vtg,
    u16* __restrict__ Pg)
{
    __shared__ u16 Xl[128 * 40];
    __shared__ u16 Wl[128 * 40];
    const int tid = threadIdx.x;
    const int lane = tid & 63, w = tid >> 6;
    const int quad = lane >> 4, ln = lane & 15;
    const int wm = w & 1, wn = w >> 1;

    const int yy = blockIdx.y;
    int sel, m0, n0;
    const u16 *Ap, *Bp;
    if (yy < 12) {
        sel = yy >> 2; n0 = (yy & 3) * 128; m0 = blockIdx.x * 128;
        Ap = Xb; Bp = (sel == 0) ? WqT : (sel == 1) ? WkT : WvT;
    } else {
        sel = 3; m0 = (blockIdx.x >> 2) * 128; n0 = (blockIdx.x & 3) * 128;
        Ap = Peb; Bp = WposT;
    }
    const int b = (m0 >> 10) & 7, tbase = m0 & 1023;

    const int sr = tid >> 2, sg = tid & 3;

    floatx4 acc[4][4];
#pragma unroll
    for (int i = 0; i < 4; ++i)
#pragma unroll
        for (int j = 0; j < 4; ++j) acc[i][j] = (floatx4){0.f, 0.f, 0.f, 0.f};

    ushort8v xq[2], wq2[2];
#pragma unroll
    for (int it = 0; it < 2; ++it) {
        int r = sr + it * 64;
        xq[it]  = *(const ushort8v*)&Ap[(size_t)(m0 + r) * 512 + sg * 8];
        wq2[it] = *(const ushort8v*)&Bp[(size_t)(n0 + r) * 512 + sg * 8];
    }

    for (int kc = 0; kc < 512; kc += 32) {
        __syncthreads();
#pragma unroll
        for (int it = 0; it < 2; ++it) {
            int r = sr + it * 64;
            *(ushort8v*)&Xl[r * 40 + sg * 8] = xq[it];
            *(ushort8v*)&Wl[r * 40 + sg * 8] = wq2[it];
        }
        __syncthreads();
        if (kc + 32 < 512) {
#pragma unroll
            for (int it = 0; it < 2; ++it) {
                int r = sr + it * 64;
                xq[it]  = *(const ushort8v*)&Ap[(size_t)(m0 + r) * 512 + kc + 32 + sg * 8];
                wq2[it] = *(const ushort8v*)&Bp[(size_t)(n0 + r) * 512 + kc + 32 + sg * 8];
            }
        }
        __builtin_amdgcn_s_setprio(1);
        bf16x8 am[4], an[4];
#pragma unroll
        for (int i = 0; i < 4; ++i)
            am[i] = *(bf16x8*)&Xl[(wm * 64 + i * 16 + ln) * 40 + quad * 8];
#pragma unroll
        for (int j = 0; j < 4; ++j)
            an[j] = *(bf16x8*)&Wl[(wn * 64 + j * 16 + ln) * 40 + quad * 8];
        if (sel != 2) {
#pragma unroll
            for (int i = 0; i < 4; ++i)
#pragma unroll
                for (int j = 0; j < 4; ++j)
                    acc[i][j] = MFMA16(an[j], am[i], acc[i][j]);
        } else {
#pragma unroll
            for (int i = 0; i < 4; ++i)
#pragma unroll
                for (int j = 0; j < 4; ++j)
                    acc[i][j] = MFMA16(am[i], an[j], acc[i][j]);
        }
        __builtin_amdgcn_s_setprio(0);
    }
    if (sel < 2) {
        u16* dst = (sel == 0) ? Qb : Kb;
#pragma unroll
        for (int i = 0; i < 4; ++i) {
            int t = tbase + wm * 64 + i * 16 + ln;
#pragma unroll
            for (int j = 0; j < 4; ++j) {
                int n = n0 + wn * 64 + j * 16 + quad * 4;
                int h = n >> 6, d = n & 63;
                ushort4 s;
                s.x = f2b(acc[i][j][0]); s.y = f2b(acc[i][j][1]);
                s.z = f2b(acc[i][j][2]); s.w = f2b(acc[i][j][3]);
                *(ushort4*)&dst[(((size_t)b * 8 + h) * 1024 + t) * 64 + d] = s;
            }
        }
    } else if (sel == 2) {
#pragma unroll
        for (int i = 0; i < 4; ++i) {
            int t4 = tbase + wm * 64 + i * 16 + quad * 4;
#pragma unroll
            for (int j = 0; j < 4; ++j) {
                int n = n0 + wn * 64 + j * 16 + ln;
                int h = n >> 6, d = n & 63;
                ushort4 s;
                s.x = f2b(acc[i][j][0]); s.y = f2b(acc[i][j][1]);
                s.z = f2b(acc[i][j][2]); s.w = f2b(acc[i][j][3]);
                *(ushort4*)&Vtg[(((size_t)b * 8 + h) * 64 + d) * 1024 + t4] = s;
            }
        }
    } else {
        // pos: P[(h*2048 + l)*64 + d]
#pragma unroll
        for (int i = 0; i < 4; ++i) {
            int l = m0 + wm * 64 + i * 16 + ln;
#pragma unroll
            for (int j = 0; j < 4; ++j) {
                int n = n0 + wn * 64 + j * 16 + quad * 4;
                int h = n >> 6, d = n & 63;
                ushort4 s;
                s.x = f2b(acc[i][j][0]); s.y = f2b(acc[i][j][1]);
                s.z = f2b(acc[i][j][2]); s.w = f2b(acc[i][j][3]);
                *(ushort4*)&Pg[(((size_t)h << 11) + l) * 64 + d] = s;
            }
        }
    }
}

// ---------------------------------------------------------------- attention
// q-bias add with the 0.125 softmax scale folded in (pow2 => scores
// bit-identical to post-scaling).
__device__ __forceinline__ bf16x8 addbias(bf16x8 q, const float* __restrict__ bias) {
    float4 a = *(const float4*)&bias[0];
    float4 b = *(const float4*)&bias[4];
    bf16x8 r;
    r[0] = (short)f2b(0.125f * (b2f((u16)q[0]) + a.x));
    r[1] = (short)f2b(0.125f * (b2f((u16)q[1]) + a.y));
    r[2] = (short)f2b(0.125f * (b2f((u16)q[2]) + a.z));
    r[3] = (short)f2b(0.125f * (b2f((u16)q[3]) + a.w));
    r[4] = (short)f2b(0.125f * (b2f((u16)q[4]) + b.x));
    r[5] = (short)f2b(0.125f * (b2f((u16)q[5]) + b.y));
    r[6] = (short)f2b(0.125f * (b2f((u16)q[6]) + b.z));
    r[7] = (short)f2b(0.125f * (b2f((u16)q[7]) + b.w));
    return r;
}

// Block = (b, h, 128 q-rows) = 4 waves x 2 sets x 16 rows. S-chunks of 64.
// Pb = 256-row ring (slot = l&255), staged 64 rows/chunk via gll16 with
// source-side XOR swizzle; read slot = quad ^ (rb&7). K/V: register
// prefetch -> stride-72 LDS (R13-proven). gw stride 84 floats.
// setprio(1) wraps the MFMA clusters (bd+ac, PV) -- register-neutral.
__global__ __launch_bounds__(256, 2) void attn_mfma(
    const u16* __restrict__ Qb,
    const u16* __restrict__ Kb, const u16* __restrict__ Vtg,
    const u16* __restrict__ P, const u64* __restrict__ Mp,
    const float* __restrict__ ub, const float* __restrict__ vb,
    u16* __restrict__ Z)
{
    __shared__ u16 Klds[64 * 72];
    __shared__ u16 Vtlds[64 * 72];
    __shared__ u16 Pb[256 * 64];
    __shared__ __align__(16) char WaveBuf[4][16 * 84 * 4];

    const int tid  = threadIdx.x;
    const int lane = tid & 63;
    const int w    = tid >> 6;
    const int quad = lane >> 4;
    const int ln   = lane & 15;

    const int bid = blockIdx.x;                    // 512 blocks
    const int xg  = bid & 7;
    const int idx = bid >> 3;
    const int bh_i = xg * 8 + (idx >> 3);
    const int t0 = (idx & 7) << 7;
    const int h  = bh_i & 7;
    const int b  = bh_i >> 3;
    const size_t bh  = (size_t)bh_i * 1024;
    const size_t bhd = (size_t)bh_i * 64;
    const int lbase0 = 896 - t0;                   // P band base for chunk 0
    size_t mprow[2];
    mprow[0] = ((size_t)b * 1024 + t0 + 16 * w + ln) * 16;
    mprow[1] = ((size_t)b * 1024 + t0 + 64 + 16 * w + ln) * 16;

    bf16x8 qu0[2], qu1[2], qv0[2], qv1[2];
#pragma unroll
    for (int c = 0; c < 2; ++c) {
        const size_t qoff = (bh + t0 + 64 * c + 16 * w + ln) * 64;
        bf16x8 q0 = *(const bf16x8*)&Qb[qoff + quad * 8];
        bf16x8 q1 = *(const bf16x8*)&Qb[qoff + 32 + quad * 8];
        qu0[c] = addbias(q0, &ub[h * 64 + quad * 8]);
        qu1[c] = addbias(q1, &ub[h * 64 + 32 + quad * 8]);
        qv0[c] = addbias(q0, &vb[h * 64 + quad * 8]);
        qv1[c] = addbias(q1, &vb[h * 64 + 32 + quad * 8]);
    }

    floatx4 O[2][4];
#pragma unroll
    for (int c = 0; c < 2; ++c)
#pragma unroll
        for (int dt = 0; dt < 4; ++dt) O[c][dt] = (floatx4){0.f, 0.f, 0.f, 0.f};
    float m_run[2] = {-3.0e38f, -3.0e38f}, l_run[2] = {0.f, 0.f};

    float* gw = (float*)&WaveBuf[w][0];
    u16*  pw  = (u16*)&WaveBuf[w][0];

    const int str = tid >> 3, stg = tid & 7;
    const int g8 = lane >> 3, s8 = lane & 7;       // gll source lane decomp
    const int pcol = ((s8 ^ g8) << 3);             // source-side XOR col
    ushort8v kq[2], vq[2];
    u64 bc0, bc1;

    // ---- prologue: P ring rows [lbase0, lbase0+192) via gll; K/V chunk 0;
    // mask bits chunk 0. All drained by the first barrier.
#pragma unroll
    for (int it = 0; it < 6; ++it) {
        int rb = lbase0 + 8 * w + 32 * it;         // 8-aligned => l&7 == lane>>3
        gll16(&P[(((size_t)h << 11) + (size_t)(rb + g8)) * 64 + pcol],
              &Pb[(rb & 255) << 6]);
    }
#pragma unroll
    for (int it = 0; it < 2; ++it) {
        int r = str + it * 32;
        kq[it] = *(const ushort8v*)&Kb[(bh + r) * 64 + stg * 8];
        vq[it] = *(const ushort8v*)&Vtg[(bhd + r) * 1024 + stg * 8];
    }
    bc0 = Mp[mprow[0]];
    bc1 = Mp[mprow[1]];

    for (int s0 = 0; s0 < 1024; s0 += 64) {
        __syncthreads();
#pragma unroll
        for (int it = 0; it < 2; ++it) {
            int r = str + it * 32;
            *(ushort8v*)&Klds[r * 72 + stg * 8] = kq[it];
            *(ushort8v*)&Vtlds[r * 72 + stg * 8] = vq[it];
        }
        __syncthreads();

        const int lb8 = (lbase0 + s0) & 255;
        u64 nb0 = 0, nb1 = 0;
        if (s0 + 64 < 1024) {
            // K/V register prefetch for next chunk
#pragma unroll
            for (int it = 0; it < 2; ++it) {
                int r = str + it * 32;
                kq[it] = *(const ushort8v*)&Kb[(bh + s0 + 64 + r) * 64 + stg * 8];
                vq[it] = *(const ushort8v*)&Vtg[(bhd + r) * 1024 + s0 + 64 + stg * 8];
            }
            // P ring: stage the 64 rows chunk i+1 adds: [lbase+192, lbase+256)
            const int lst = lbase0 + s0 + 192;
#pragma unroll
            for (int it = 0; it < 2; ++it) {
                int rb = lst + 8 * w + 32 * it;
                gll16(&P[(((size_t)h << 11) + (size_t)(rb + g8)) * 64 + pcol],
                      &Pb[(rb & 255) << 6]);
            }
            nb0 = Mp[mprow[0] + (s0 >> 6) + 1];
            nb1 = Mp[mprow[1] + (s0 >> 6) + 1];
        }

        bf16x8 vf0[4], vf1[4];
#pragma unroll
        for (int dt = 0; dt < 4; ++dt) {
            int vr = dt * 16 + ln;
            vf0[dt] = *(bf16x8*)&Vtlds[vr * 72 + quad * 8];
            vf1[dt] = *(bf16x8*)&Vtlds[vr * 72 + 32 + quad * 8];
        }

#pragma unroll
        for (int c = 0; c < 2; ++c) {
            const u64 bits = (c == 0) ? bc0 : bc1;
            const int rb0 = 112 - 64 * c - 16 * w;
            __builtin_amdgcn_s_setprio(1);
#pragma unroll
            for (int jt = 0; jt < 5; ++jt) {
                int rb = rb0 + jt * 16 + ln;
                int prow = ((lb8 + rb) & 255) << 6;
                bf16x8 a0 = *(bf16x8*)&Pb[prow + ((quad ^ (rb & 7)) << 3)];
                bf16x8 a1 = *(bf16x8*)&Pb[prow + (((4 + quad) ^ (rb & 7)) << 3)];
                floatx4 g = {0.f, 0.f, 0.f, 0.f};
                g = MFMA16(a0, qv0[c], g);
                g = MFMA16(a1, qv1[c], g);
                *(floatx4*)&gw[ln * 84 + jt * 16 + quad * 4] = g;
            }
            floatx4 cac[4];
#pragma unroll
            for (int st = 0; st < 4; ++st) {
                int kr = st * 16 + ln;
                bf16x8 a0 = *(bf16x8*)&Klds[kr * 72 + quad * 8];
                bf16x8 a1 = *(bf16x8*)&Klds[kr * 72 + 32 + quad * 8];
                floatx4 cc = {0.f, 0.f, 0.f, 0.f};
                cc = MFMA16(a0, qu0[c], cc);
                cc = MFMA16(a1, qu1[c], cc);
                cac[st] = cc;
            }
            __builtin_amdgcn_s_setprio(0);
            float sc[4][4];
            float cmax = -3.0e38f;
#pragma unroll
            for (int st = 0; st < 4; ++st) {
                int j0 = st * 16 + quad * 4 + 15 - ln;
#pragma unroll
                for (int r = 0; r < 4; ++r) {
                    float v = cac[st][r] + gw[ln * 84 + j0 + r];
                    int ss = st * 16 + quad * 4 + r;
                    v = ((bits >> ss) & 1ull) ? v : -1.0e30f;
                    sc[st][r] = v;
                    cmax = fmaxf(cmax, v);
                }
            }
            cmax = fmaxf(cmax, __shfl_xor(cmax, 16));
            cmax = fmaxf(cmax, __shfl_xor(cmax, 32));
            float m_new = fmaxf(m_run[c], cmax);
            float alpha = __expf(m_run[c] - m_new);
            float psum = 0.f;
#pragma unroll
            for (int st = 0; st < 4; ++st) {
                float p0 = __expf(sc[st][0] - m_new);
                float p1 = __expf(sc[st][1] - m_new);
                float p2 = __expf(sc[st][2] - m_new);
                float p3 = __expf(sc[st][3] - m_new);
                psum += (p0 + p1) + (p2 + p3);
                ushort4 pk;
                pk.x = f2b(p0); pk.y = f2b(p1); pk.z = f2b(p2); pk.w = f2b(p3);
                *(ushort4*)&pw[ln * 72 + st * 16 + quad * 4] = pk;
            }
            psum += __shfl_xor(psum, 16);
            psum += __shfl_xor(psum, 32);
            l_run[c] = l_run[c] * alpha + psum;
            m_run[c] = m_new;
            float a0s = __shfl(alpha, quad * 4 + 0);
            float a1s = __shfl(alpha, quad * 4 + 1);
            float a2s = __shfl(alpha, quad * 4 + 2);
            float a3s = __shfl(alpha, quad * 4 + 3);
#pragma unroll
            for (int dt = 0; dt < 4; ++dt) {
                O[c][dt][0] *= a0s; O[c][dt][1] *= a1s;
                O[c][dt][2] *= a2s; O[c][dt][3] *= a3s;
            }
            bf16x8 pa0 = *(bf16x8*)&pw[ln * 72 + quad * 8];
            bf16x8 pa1 = *(bf16x8*)&pw[ln * 72 + 32 + quad * 8];
            __builtin_amdgcn_s_setprio(1);
#pragma unroll
            for (int dt = 0; dt < 4; ++dt) {
                O[c][dt] = MFMA16(pa0, vf0[dt], O[c][dt]);
                O[c][dt] = MFMA16(pa1, vf1[dt], O[c][dt]);
            }
            __builtin_amdgcn_s_setprio(0);
        }
        bc0 = nb0; bc1 = nb1;
    }
#pragma unroll
    for (int c = 0; c < 2; ++c) {
        float li[4];
#pragma unroll
        for (int r = 0; r < 4; ++r) li[r] = 1.0f / __shfl(l_run[c], quad * 4 + r);
#pragma unroll
        for (int r = 0; r < 4; ++r) {
            size_t zo = ((size_t)b * 1024 + t0 + 64 * c + 16 * w + quad * 4 + r) * 512
                      + h * 64 + ln;
            Z[zo + 0]  = f2b(O[c][0][r] * li[r]);
            Z[zo + 16] = f2b(O[c][1][r] * li[r]);
            Z[zo + 32] = f2b(O[c][2][r] * li[r]);
            Z[zo + 48] = f2b(O[c][3][r] * li[r]);
        }
    }
}

// ---------------------------------------------------------------- out MFMA
__global__ __launch_bounds__(256, 2) void out_mfma(
    const u16* __restrict__ Zb, const u16* __restrict__ WoT,
    float* __restrict__ out)
{
    __shared__ u16 Xl[128 * 40];
    __shared__ u16 Wl[128 * 40];
    const int tid = threadIdx.x;
    const int lane = tid & 63, w = tid >> 6;
    const int quad = lane >> 4, ln = lane & 15;
    const int wm = w & 1, wn = w >> 1;
    const int m0 = blockIdx.x * 128;
    const int n0 = blockIdx.y * 128;
    const int sr = tid >> 2, sg = tid & 3;

    floatx4 acc[4][4];
#pragma unroll
    for (int i = 0; i < 4; ++i)
#pragma unroll
        for (int j = 0; j < 4; ++j) acc[i][j] = (floatx4){0.f, 0.f, 0.f, 0.f};

    ushort8v xq[2], wq2[2];
#pragma unroll
    for (int it = 0; it < 2; ++it) {
        int r = sr + it * 64;
        xq[it]  = *(const ushort8v*)&Zb[(size_t)(m0 + r) * 512 + sg * 8];
        wq2[it] = *(const ushort8v*)&WoT[(size_t)(n0 + r) * 512 + sg * 8];
    }

    for (int kc = 0; kc < 512; kc += 32) {
        __syncthreads();
#pragma unroll
        for (int it = 0; it < 2; ++it) {
            int r = sr + it * 64;
            *(ushort8v*)&Xl[r * 40 + sg * 8] = xq[it];
            *(ushort8v*)&Wl[r * 40 + sg * 8] = wq2[it];
        }
        __syncthreads();
        if (kc + 32 < 512) {
#pragma unroll
            for (int it = 0; it < 2; ++it) {
                int r = sr + it * 64;
                xq[it]  = *(const ushort8v*)&Zb[(size_t)(m0 + r) * 512 + kc + 32 + sg * 8];
                wq2[it] = *(const ushort8v*)&WoT[(size_t)(n0 + r) * 512 + kc + 32 + sg * 8];
            }
        }
        __builtin_amdgcn_s_setprio(1);
        bf16x8 am[4], an[4];
#pragma unroll
        for (int i = 0; i < 4; ++i)
            am[i] = *(bf16x8*)&Xl[(wm * 64 + i * 16 + ln) * 40 + quad * 8];
#pragma unroll
        for (int j = 0; j < 4; ++j)
            an[j] = *(bf16x8*)&Wl[(wn * 64 + j * 16 + ln) * 40 + quad * 8];
#pragma unroll
        for (int i = 0; i < 4; ++i)
#pragma unroll
            for (int j = 0; j < 4; ++j)
                acc[i][j] = MFMA16(an[j], am[i], acc[i][j]);
        __builtin_amdgcn_s_setprio(0);
    }
#pragma unroll
    for (int i = 0; i < 4; ++i) {
        int m = m0 + wm * 64 + i * 16 + ln;
#pragma unroll
        for (int j = 0; j < 4; ++j) {
            int n = n0 + wn * 64 + j * 16 + quad * 4;
            float4 s;
            s.x = acc[i][j][0]; s.y = acc[i][j][1];
            s.z = acc[i][j][2]; s.w = acc[i][j][3];
            *(float4*)&out[(size_t)m * 512 + n] = s;
        }
    }
}

// ---------------------------------------------------------------- launch
extern "C" void kernel_launch(void* const* d_in, const int* in_sizes, int n_in,
                              void* d_out, int out_size, void* d_ws, size_t ws_size,
                              hipStream_t stream) {
    const float* xs   = (const float*)d_in[0];
    const int*   mask = (const int*)d_in[1];
    const float* Wq   = (const float*)d_in[2];
    const float* Wk   = (const float*)d_in[3];
    const float* Wv   = (const float*)d_in[4];
    const float* Wpos = (const float*)d_in[5];
    const float* Wout = (const float*)d_in[6];
    const float* ub   = (const float*)d_in[7];
    const float* vb   = (const float*)d_in[8];
    float* out = (float*)d_out;

    u16* Qb  = (u16*)d_ws;                   // 4194304
    u16* Kb  = Qb + 4194304;                 // 4194304
    u16* Vtg = Kb + 4194304;                 // 4194304
    u16* Pg  = Vtg + 4194304;                // 8*2048*64 = 1048576
    u16* XZ  = Pg + 1048576;                 // 4194304 (Xb, then reused as Z)
    u16* WT  = XZ + 4194304;                 // 5*262144 = 1310720
    u16* WqT = WT;
    u16* WkT = WT + 262144;
    u16* WvT = WT + 524288;
    u16* WoT = WT + 786432;
    u16* WposT = WT + 1048576;
    u16* Peb = WT + 1310720;                 // 2048*512 = 1048576
    u64* Mp  = (u64*)(Peb + 1048576);        // 131072 u64

    prep_kernel<<<4928, 256, 0, stream>>>(xs, XZ, Wq, Wk, Wv, Wout, Wpos, WT,
                                          mask, Mp, Peb);
    qkv_mfma<<<dim3(64, 13), 256, 0, stream>>>(XZ, WqT, WkT, WvT, Peb, WposT,
                                               Qb, Kb, Vtg, Pg);
    attn_mfma<<<512, 256, 0, stream>>>(Qb, Kb, Vtg, Pg, Mp, ub, vb, XZ);
    out_mfma<<<dim3(64, 4), 256, 0, stream>>>(XZ, WoT, out);
}

// Round 12
// 213.140 us; speedup vs baseline: 1.3376x; 1.0124x over previous
//
#include <hip/hip_runtime.h>
#include <hip/hip_bf16.h>

// Transformer-XL relative MHA. fp32 in/out, bf16 intermediates in d_ws.
// B=8 T=1024 D_MODEL=512 H=8 DH=64.
// R22 = R21 (best, 215.8us) + qkv_mfma BK 32->64: halves barrier count
// (16->8 K-iters), doubles MFMA per drain (16->32). Staging regs 16->32
// VGPR (live ~140 << 256 cap at 2 waves/SIMD -- NOT R19's 3-wave 84-cap
// spill); LDS 20->36KB (72KB/CU at 2 blocks, occupancy unchanged, avoids
// m132's BK=128 cliff). Stride-72 u16 rows: 144B keeps 16B alignment,
// uniform 8-lanes/16B-slot (wave64 b128 floor) for writes+reads, same
// conflict class as proven stride-40. attn/prep/out frozen at R21
// (attn canary: 71.7us / VGPR 120 / 6.8e6 conflicts / WRITE 8MB).
// Session rules (R12/R15/R17/R18/R19 reverted): ~120-150 VGPR @ 2
// blocks/CU; reg-prefetch two-barrier pipelines; conflicts at floor.
// Rel-shift identity: bd[t,s] = q_v[t] . p[1023 - t + s].

typedef unsigned short u16;
typedef unsigned long long u64;
typedef unsigned int u32;
typedef __attribute__((ext_vector_type(8))) short bf16x8;
typedef __attribute__((ext_vector_type(8))) unsigned short ushort8v;
typedef __attribute__((ext_vector_type(4))) float floatx4;

__device__ __forceinline__ float b2f(u16 u) {
    union { unsigned int i; float f; } x; x.i = ((unsigned int)u) << 16; return x.f;
}
__device__ __forceinline__ u16 f2b(float f) {
    __hip_bfloat16 h = __float2bfloat16(f);
    return *reinterpret_cast<u16*>(&h);
}

#define MFMA16(a, b, c) __builtin_amdgcn_mfma_f32_16x16x32_bf16(a, b, c, 0, 0, 0)

// async 16B/lane global->LDS (lds base must be wave-uniform; lane i lands
// at base + i*16)
__device__ __forceinline__ void gll16(const u16* g, u16* l) {
    __builtin_amdgcn_global_load_lds(
        (const __attribute__((address_space(1))) u32*)g,
        (__attribute__((address_space(3))) u32*)l, 16, 0, 0);
}

// ---------------------------------------------------------------- prep
// [0,2048): castX ; [2048,2368): castW x5 ; [2368,4416): maskpack ;
// [4416,4928): pe-gen (bf16 sinusoid table, 2048 rows x 512)
__global__ __launch_bounds__(256) void prep_kernel(
    const float* __restrict__ X, u16* __restrict__ Xb,
    const float* __restrict__ W0, const float* __restrict__ W1,
    const float* __restrict__ W2, const float* __restrict__ W3,
    const float* __restrict__ W4, u16* __restrict__ WT,
    const int* __restrict__ mask, u64* __restrict__ Mp,
    u16* __restrict__ Peb)
{
    const int bi = blockIdx.x;
    const int tid = threadIdx.x;
    if (bi < 2048) {
        size_t i = ((size_t)bi * 256 + tid) * 8;
        float4 a = *(const float4*)&X[i];
        float4 b = *(const float4*)&X[i + 4];
        ushort8v s;
        s[0] = f2b(a.x); s[1] = f2b(a.y); s[2] = f2b(a.z); s[3] = f2b(a.w);
        s[4] = f2b(b.x); s[5] = f2b(b.y); s[6] = f2b(b.z); s[7] = f2b(b.w);
        *(ushort8v*)&Xb[i] = s;
    } else if (bi < 2368) {
        __shared__ float t[64][68];
        const int li = bi - 2048;
        const int m = li >> 6;
        const float* src = (m == 0) ? W0 : (m == 1) ? W1 : (m == 2) ? W2
                         : (m == 3) ? W3 : W4;
        u16* dst = WT + (size_t)m * 262144;
        const int sub = li & 63;
        const int k0 = ((sub >> 3) & 7) * 64, n0 = (sub & 7) * 64;
        const int r = tid >> 4, c = tid & 15;
#pragma unroll
        for (int rr = 0; rr < 64; rr += 16) {
            float4 v = *(const float4*)&src[(size_t)(k0 + r + rr) * 512 + n0 + 4 * c];
            t[r + rr][4 * c + 0] = v.x;
            t[r + rr][4 * c + 1] = v.y;
            t[r + rr][4 * c + 2] = v.z;
            t[r + rr][4 * c + 3] = v.w;
        }
        __syncthreads();
        const int nrow = tid >> 2, kc = (tid & 3) * 16;
        ushort8v s0, s1;
#pragma unroll
        for (int e = 0; e < 8; ++e) {
            s0[e] = f2b(t[kc + e][nrow]);
            s1[e] = f2b(t[kc + 8 + e][nrow]);
        }
        *(ushort8v*)&dst[(size_t)(n0 + nrow) * 512 + k0 + kc] = s0;
        *(ushort8v*)&dst[(size_t)(n0 + nrow) * 512 + k0 + kc + 8] = s1;
    } else if (bi < 4416) {
        const int lane = tid & 63, w = tid >> 6;
        const int row = (bi - 2368) * 4 + w;
#pragma unroll
        for (int j = 0; j < 16; ++j) {
            int v = mask[(size_t)row * 1024 + j * 64 + lane];
            u64 bits = __ballot(v != 0);
            if (lane == j) Mp[(size_t)row * 16 + j] = bits;
        }
    } else {
        // ---- pe-gen: row l (wave-per-row), lane covers 8 consecutive k.
        // pe[l][2i] = sin(pos*invf_i), pe[l][2i+1] = cos(...), pos=min(l,2046)-1023
        // fast trig: angle err ~1e-4 << bf16 rounding of the table.
        const int lane = tid & 63, w = tid >> 6;
        const int l = (bi - 4416) * 4 + w;             // 0..2047
        const int lc = (l > 2046) ? 2046 : l;
        const float pos = (float)(lc - 1023);
        ushort8v s;
#pragma unroll
        for (int e = 0; e < 8; ++e) {
            int k = (lane << 3) + e;
            int i = k >> 1;
            float invf = __expf(-0.035977892f * (float)i);   // ln(1e4)/256
            float ang = pos * invf;
            float v = (k & 1) ? __cosf(ang) : __sinf(ang);
            s[e] = f2b(v);
        }
        *(ushort8v*)&Peb[(size_t)l * 512 + (lane << 3)] = s;
    }
}

// ---------------------------------------------------------------- qkv+pos MFMA
// grid (64, 13): y<12 -> QKV (y: 0-3 Q, 4-7 K, 8-11 V; n0=(y&3)*128,
// m0=x*128 over xs). y==12 -> pos GEMM: m0=(x>>2)*128 over pe (M=2048),
// n0=(x&3)*128; writes P[h][l(stride2048)][d].
// R22: BK=64, stride-72 tiles, 8 K-iters, ks-unrolled 2x16 MFMA.
__global__ __launch_bounds__(256, 2) void qkv_mfma(
    const u16* __restrict__ Xb, const u16* __restrict__ WqT,
    const u16* __restrict__ WkT, const u16* __restrict__ WvT,
    const u16* __restrict__ Peb, const u16* __restrict__ WposT,
    u16* __restrict__ Qb, u16* __restrict__ Kb, u16* __restrict__ Vtg,
    u16* __restrict__ Pg)
{
    __shared__ u16 Xl[128 * 72];
    __shared__ u16 Wl[128 * 72];
    const int tid = threadIdx.x;
    const int lane = tid & 63, w = tid >> 6;
    const int quad = lane >> 4, ln = lane & 15;
    const int wm = w & 1, wn = w >> 1;

    const int yy = blockIdx.y;
    int sel, m0, n0;
    const u16 *Ap, *Bp;
    if (yy < 12) {
        sel = yy >> 2; n0 = (yy & 3) * 128; m0 = blockIdx.x * 128;
        Ap = Xb; Bp = (sel == 0) ? WqT : (sel == 1) ? WkT : WvT;
    } else {
        sel = 3; m0 = (blockIdx.x >> 2) * 128; n0 = (blockIdx.x & 3) * 128;
        Ap = Peb; Bp = WposT;
    }
    const int b = (m0 >> 10) & 7, tbase = m0 & 1023;

    const int sr = tid >> 2, sg = tid & 3;

    floatx4 acc[4][4];
#pragma unroll
    for (int i = 0; i < 4; ++i)
#pragma unroll
        for (int j = 0; j < 4; ++j) acc[i][j] = (floatx4){0.f, 0.f, 0.f, 0.f};

    ushort8v xq[4], wq2[4];
#pragma unroll
    for (int it = 0; it < 2; ++it)
#pragma unroll
        for (int ks = 0; ks < 2; ++ks) {
            int r = sr + it * 64;
            xq[it * 2 + ks]  = *(const ushort8v*)&Ap[(size_t)(m0 + r) * 512 + ks * 32 + sg * 8];
            wq2[it * 2 + ks] = *(const ushort8v*)&Bp[(size_t)(n0 + r) * 512 + ks * 32 + sg * 8];
        }

    for (int kc = 0; kc < 512; kc += 64) {
        __syncthreads();
#pragma unroll
        for (int it = 0; it < 2; ++it)
#pragma unroll
            for (int ks = 0; ks < 2; ++ks) {
                int r = sr + it * 64;
                *(ushort8v*)&Xl[r * 72 + ks * 32 + sg * 8] = xq[it * 2 + ks];
                *(ushort8v*)&Wl[r * 72 + ks * 32 + sg * 8] = wq2[it * 2 + ks];
            }
        __syncthreads();
        if (kc + 64 < 512) {
#pragma unroll
            for (int it = 0; it < 2; ++it)
#pragma unroll
                for (int ks = 0; ks < 2; ++ks) {
                    int r = sr + it * 64;
                    xq[it * 2 + ks]  = *(const ushort8v*)&Ap[(size_t)(m0 + r) * 512 + kc + 64 + ks * 32 + sg * 8];
                    wq2[it * 2 + ks] = *(const ushort8v*)&Bp[(size_t)(n0 + r) * 512 + kc + 64 + ks * 32 + sg * 8];
                }
        }
        __builtin_amdgcn_s_setprio(1);
#pragma unroll
        for (int ks = 0; ks < 2; ++ks) {
            bf16x8 am[4], an[4];
#pragma unroll
            for (int i = 0; i < 4; ++i)
                am[i] = *(bf16x8*)&Xl[(wm * 64 + i * 16 + ln) * 72 + ks * 32 + quad * 8];
#pragma unroll
            for (int j = 0; j < 4; ++j)
                an[j] = *(bf16x8*)&Wl[(wn * 64 + j * 16 + ln) * 72 + ks * 32 + quad * 8];
            if (sel != 2) {
#pragma unroll
                for (int i = 0; i < 4; ++i)
#pragma unroll
                    for (int j = 0; j < 4; ++j)
                        acc[i][j] = MFMA16(an[j], am[i], acc[i][j]);
            } else {
#pragma unroll
                for (int i = 0; i < 4; ++i)
#pragma unroll
                    for (int j = 0; j < 4; ++j)
                        acc[i][j] = MFMA16(am[i], an[j], acc[i][j]);
            }
        }
        __builtin_amdgcn_s_setprio(0);
    }
    if (sel < 2) {
        u16* dst = (sel == 0) ? Qb : Kb;
#pragma unroll
        for (int i = 0; i < 4; ++i) {
            int t = tbase + wm * 64 + i * 16 + ln;
#pragma unroll
            for (int j = 0; j < 4; ++j) {
                int n = n0 + wn * 64 + j * 16 + quad * 4;
                int h = n >> 6, d = n & 63;
                ushort4 s;
                s.x = f2b(acc[i][j][0]); s.y = f2b(acc[i][j][1]);
                s.z = f2b(acc[i][j][2]); s.w = f2b(acc[i][j][3]);
                *(ushort4*)&dst[(((size_t)b * 8 + h) * 1024 + t) * 64 + d] = s;
            }
        }
    } else if (sel == 2) {
#pragma unroll
        for (int i = 0; i < 4; ++i) {
            int t4 = tbase + wm * 64 + i * 16 + quad * 4;
#pragma unroll
            for (int j = 0; j < 4; ++j) {
                int n = n0 + wn * 64 + j * 16 + ln;
                int h = n >> 6, d = n & 63;
                ushort4 s;
                s.x = f2b(acc[i][j][0]); s.y = f2b(acc[i][j][1]);
                s.z = f2b(acc[i][j][2]); s.w = f2b(acc[i][j][3]);
                *(ushort4*)&Vtg[(((size_t)b * 8 + h) * 64 + d) * 1024 + t4] = s;
            }
        }
    } else {
        // pos: P[(h*2048 + l)*64 + d]
#pragma unroll
        for (int i = 0; i < 4; ++i) {
            int l = m0 + wm * 64 + i * 16 + ln;
#pragma unroll
            for (int j = 0; j < 4; ++j) {
                int n = n0 + wn * 64 + j * 16 + quad * 4;
                int h = n >> 6, d = n & 63;
                ushort4 s;
                s.x = f2b(acc[i][j][0]); s.y = f2b(acc[i][j][1]);
                s.z = f2b(acc[i][j][2]); s.w = f2b(acc[i][j][3]);
                *(ushort4*)&Pg[(((size_t)h << 11) + l) * 64 + d] = s;
            }
        }
    }
}

// ---------------------------------------------------------------- attention
// q-bias add with the 0.125 softmax scale folded in (pow2 => scores
// bit-identical to post-scaling).
__device__ __forceinline__ bf16x8 addbias(bf16x8 q, const float* __restrict__ bias) {
    float4 a = *(const float4*)&bias[0];
    float4 b = *(const float4*)&bias[4];
    bf16x8 r;
    r[0] = (short)f2b(0.125f * (b2f((u16)q[0]) + a.x));
    r[1] = (short)f2b(0.125f * (b2f((u16)q[1]) + a.y));
    r[2] = (short)f2b(0.125f * (b2f((u16)q[2]) + a.z));
    r[3] = (short)f2b(0.125f * (b2f((u16)q[3]) + a.w));
    r[4] = (short)f2b(0.125f * (b2f((u16)q[4]) + b.x));
    r[5] = (short)f2b(0.125f * (b2f((u16)q[5]) + b.y));
    r[6] = (short)f2b(0.125f * (b2f((u16)q[6]) + b.z));
    r[7] = (short)f2b(0.125f * (b2f((u16)q[7]) + b.w));
    return r;
}

// Block = (b, h, 128 q-rows) = 4 waves x 2 sets x 16 rows. S-chunks of 64.
// Pb = 256-row ring (slot = l&255), staged 64 rows/chunk via gll16 with
// source-side XOR swizzle; read slot = quad ^ (rb&7). K/V: register
// prefetch -> stride-72 LDS (R13-proven). gw stride 84 floats.
// setprio(1) wraps the MFMA clusters (bd+ac, PV) -- register-neutral.
__global__ __launch_bounds__(256, 2) void attn_mfma(
    const u16* __restrict__ Qb,
    const u16* __restrict__ Kb, const u16* __restrict__ Vtg,
    const u16* __restrict__ P, const u64* __restrict__ Mp,
    const float* __restrict__ ub, const float* __restrict__ vb,
    u16* __restrict__ Z)
{
    __shared__ u16 Klds[64 * 72];
    __shared__ u16 Vtlds[64 * 72];
    __shared__ u16 Pb[256 * 64];
    __shared__ __align__(16) char WaveBuf[4][16 * 84 * 4];

    const int tid  = threadIdx.x;
    const int lane = tid & 63;
    const int w    = tid >> 6;
    const int quad = lane >> 4;
    const int ln   = lane & 15;

    const int bid = blockIdx.x;                    // 512 blocks
    const int xg  = bid & 7;
    const int idx = bid >> 3;
    const int bh_i = xg * 8 + (idx >> 3);
    const int t0 = (idx & 7) << 7;
    const int h  = bh_i & 7;
    const int b  = bh_i >> 3;
    const size_t bh  = (size_t)bh_i * 1024;
    const size_t bhd = (size_t)bh_i * 64;
    const int lbase0 = 896 - t0;                   // P band base for chunk 0
    size_t mprow[2];
    mprow[0] = ((size_t)b * 1024 + t0 + 16 * w + ln) * 16;
    mprow[1] = ((size_t)b * 1024 + t0 + 64 + 16 * w + ln) * 16;

    bf16x8 qu0[2], qu1[2], qv0[2], qv1[2];
#pragma unroll
    for (int c = 0; c < 2; ++c) {
        const size_t qoff = (bh + t0 + 64 * c + 16 * w + ln) * 64;
        bf16x8 q0 = *(const bf16x8*)&Qb[qoff + quad * 8];
        bf16x8 q1 = *(const bf16x8*)&Qb[qoff + 32 + quad * 8];
        qu0[c] = addbias(q0, &ub[h * 64 + quad * 8]);
        qu1[c] = addbias(q1, &ub[h * 64 + 32 + quad * 8]);
        qv0[c] = addbias(q0, &vb[h * 64 + quad * 8]);
        qv1[c] = addbias(q1, &vb[h * 64 + 32 + quad * 8]);
    }

    floatx4 O[2][4];
#pragma unroll
    for (int c = 0; c < 2; ++c)
#pragma unroll
        for (int dt = 0; dt < 4; ++dt) O[c][dt] = (floatx4){0.f, 0.f, 0.f, 0.f};
    float m_run[2] = {-3.0e38f, -3.0e38f}, l_run[2] = {0.f, 0.f};

    float* gw = (float*)&WaveBuf[w][0];
    u16*  pw  = (u16*)&WaveBuf[w][0];

    const int str = tid >> 3, stg = tid & 7;
    const int g8 = lane >> 3, s8 = lane & 7;       // gll source lane decomp
    const int pcol = ((s8 ^ g8) << 3);             // source-side XOR col
    ushort8v kq[2], vq[2];
    u64 bc0, bc1;

    // ---- prologue: P ring rows [lbase0, lbase0+192) via gll; K/V chunk 0;
    // mask bits chunk 0. All drained by the first barrier.
#pragma unroll
    for (int it = 0; it < 6; ++it) {
        int rb = lbase0 + 8 * w + 32 * it;         // 8-aligned => l&7 == lane>>3
        gll16(&P[(((size_t)h << 11) + (size_t)(rb + g8)) * 64 + pcol],
              &Pb[(rb & 255) << 6]);
    }
#pragma unroll
    for (int it = 0; it < 2; ++it) {
        int r = str + it * 32;
        kq[it] = *(const ushort8v*)&Kb[(bh + r) * 64 + stg * 8];
        vq[it] = *(const ushort8v*)&Vtg[(bhd + r) * 1024 + stg * 8];
    }
    bc0 = Mp[mprow[0]];
    bc1 = Mp[mprow[1]];

    for (int s0 = 0; s0 < 1024; s0 += 64) {
        __syncthreads();
#pragma unroll
        for (int it = 0; it < 2; ++it) {
            int r = str + it * 32;
            *(ushort8v*)&Klds[r * 72 + stg * 8] = kq[it];
            *(ushort8v*)&Vtlds[r * 72 + stg * 8] = vq[it];
        }
        __syncthreads();

        const int lb8 = (lbase0 + s0) & 255;
        u64 nb0 = 0, nb1 = 0;
        if (s0 + 64 < 1024) {
            // K/V register prefetch for next chunk
#pragma unroll
            for (int it = 0; it < 2; ++it) {
                int r = str + it * 32;
                kq[it] = *(const ushort8v*)&Kb[(bh + s0 + 64 + r) * 64 + stg * 8];
                vq[it] = *(const ushort8v*)&Vtg[(bhd + r) * 1024 + s0 + 64 + stg * 8];
            }
            // P ring: stage the 64 rows chunk i+1 adds: [lbase+192, lbase+256)
            const int lst = lbase0 + s0 + 192;
#pragma unroll
            for (int it = 0; it < 2; ++it) {
                int rb = lst + 8 * w + 32 * it;
                gll16(&P[(((size_t)h << 11) + (size_t)(rb + g8)) * 64 + pcol],
                      &Pb[(rb & 255) << 6]);
            }
            nb0 = Mp[mprow[0] + (s0 >> 6) + 1];
            nb1 = Mp[mprow[1] + (s0 >> 6) + 1];
        }

        bf16x8 vf0[4], vf1[4];
#pragma unroll
        for (int dt = 0; dt < 4; ++dt) {
            int vr = dt * 16 + ln;
            vf0[dt] = *(bf16x8*)&Vtlds[vr * 72 + quad * 8];
            vf1[dt] = *(bf16x8*)&Vtlds[vr * 72 + 32 + quad * 8];
        }

#pragma unroll
        for (int c = 0; c < 2; ++c) {
            const u64 bits = (c == 0) ? bc0 : bc1;
            const int rb0 = 112 - 64 * c - 16 * w;
            __builtin_amdgcn_s_setprio(1);
#pragma unroll
            for (int jt = 0; jt < 5; ++jt) {
                int rb = rb0 + jt * 16 + ln;
                int prow = ((lb8 + rb) & 255) << 6;
                bf16x8 a0 = *(bf16x8*)&Pb[prow + ((quad ^ (rb & 7)) << 3)];
                bf16x8 a1 = *(bf16x8*)&Pb[prow + (((4 + quad) ^ (rb & 7)) << 3)];
                floatx4 g = {0.f, 0.f, 0.f, 0.f};
                g = MFMA16(a0, qv0[c], g);
                g = MFMA16(a1, qv1[c], g);
                *(floatx4*)&gw[ln * 84 + jt * 16 + quad * 4] = g;
            }
            floatx4 cac[4];
#pragma unroll
            for (int st = 0; st < 4; ++st) {
                int kr = st * 16 + ln;
                bf16x8 a0 = *(bf16x8*)&Klds[kr * 72 + quad * 8];
                bf16x8 a1 = *(bf16x8*)&Klds[kr * 72 + 32 + quad * 8];
                floatx4 cc = {0.f, 0.f, 0.f, 0.f};
                cc = MFMA16(a0, qu0[c], cc);
                cc = MFMA16(a1, qu1[c], cc);
                cac[st] = cc;
            }
            __builtin_amdgcn_s_setprio(0);
            float sc[4][4];
            float cmax = -3.0e38f;
#pragma unroll
            for (int st = 0; st < 4; ++st) {
                int j0 = st * 16 + quad * 4 + 15 - ln;
#pragma unroll
                for (int r = 0; r < 4; ++r) {
                    float v = cac[st][r] + gw[ln * 84 + j0 + r];
                    int ss = st * 16 + quad * 4 + r;
                    v = ((bits >> ss) & 1ull) ? v : -1.0e30f;
                    sc[st][r] = v;
                    cmax = fmaxf(cmax, v);
                }
            }
            cmax = fmaxf(cmax, __shfl_xor(cmax, 16));
            cmax = fmaxf(cmax, __shfl_xor(cmax, 32));
            float m_new = fmaxf(m_run[c], cmax);
            float alpha = __expf(m_run[c] - m_new);
            float psum = 0.f;
#pragma unroll
            for (int st = 0; st < 4; ++st) {
                float p0 = __expf(sc[st][0] - m_new);
                float p1 = __expf(sc[st][1] - m_new);
                float p2 = __expf(sc[st][2] - m_new);
                float p3 = __expf(sc[st][3] - m_new);
                psum += (p0 + p1) + (p2 + p3);
                ushort4 pk;
                pk.x = f2b(p0); pk.y = f2b(p1); pk.z = f2b(p2); pk.w = f2b(p3);
                *(ushort4*)&pw[ln * 72 + st * 16 + quad * 4] = pk;
            }
            psum += __shfl_xor(psum, 16);
            psum += __shfl_xor(psum, 32);
            l_run[c] = l_run[c] * alpha + psum;
            m_run[c] = m_new;
            float a0s = __shfl(alpha, quad * 4 + 0);
            float a1s = __shfl(alpha, quad * 4 + 1);
            float a2s = __shfl(alpha, quad * 4 + 2);
            float a3s = __shfl(alpha, quad * 4 + 3);
#pragma unroll
            for (int dt = 0; dt < 4; ++dt) {
                O[c][dt][0] *= a0s; O[c][dt][1] *= a1s;
                O[c][dt][2] *= a2s; O[c][dt][3] *= a3s;
            }
            bf16x8 pa0 = *(bf16x8*)&pw[ln * 72 + quad * 8];
            bf16x8 pa1 = *(bf16x8*)&pw[ln * 72 + 32 + quad * 8];
            __builtin_amdgcn_s_setprio(1);
#pragma unroll
            for (int dt = 0; dt < 4; ++dt) {
                O[c][dt] = MFMA16(pa0, vf0[dt], O[c][dt]);
                O[c][dt] = MFMA16(pa1, vf1[dt], O[c][dt]);
            }
            __builtin_amdgcn_s_setprio(0);
        }
        bc0 = nb0; bc1 = nb1;
    }
#pragma unroll
    for (int c = 0; c < 2; ++c) {
        float li[4];
#pragma unroll
        for (int r = 0; r < 4; ++r) li[r] = 1.0f / __shfl(l_run[c], quad * 4 + r);
#pragma unroll
        for (int r = 0; r < 4; ++r) {
            size_t zo = ((size_t)b * 1024 + t0 + 64 * c + 16 * w + quad * 4 + r) * 512
                      + h * 64 + ln;
            Z[zo + 0]  = f2b(O[c][0][r] * li[r]);
            Z[zo + 16] = f2b(O[c][1][r] * li[r]);
            Z[zo + 32] = f2b(O[c][2][r] * li[r]);
            Z[zo + 48] = f2b(O[c][3][r] * li[r]);
        }
    }
}

// ---------------------------------------------------------------- out MFMA
__global__ __launch_bounds__(256, 2) void out_mfma(
    const u16* __restrict__ Zb, const u16* __restrict__ WoT,
    float* __restrict__ out)
{
    __shared__ u16 Xl[128 * 40];
    __shared__ u16 Wl[128 * 40];
    const int tid = threadIdx.x;
    const int lane = tid & 63, w = tid >> 6;
    const int quad = lane >> 4, ln = lane & 15;
    const int wm = w & 1, wn = w >> 1;
    const int m0 = blockIdx.x * 128;
    const int n0 = blockIdx.y * 128;
    const int sr = tid >> 2, sg = tid & 3;

    floatx4 acc[4][4];
#pragma unroll
    for (int i = 0; i < 4; ++i)
#pragma unroll
        for (int j = 0; j < 4; ++j) acc[i][j] = (floatx4){0.f, 0.f, 0.f, 0.f};

    ushort8v xq[2], wq2[2];
#pragma unroll
    for (int it = 0; it < 2; ++it) {
        int r = sr + it * 64;
        xq[it]  = *(const ushort8v*)&Zb[(size_t)(m0 + r) * 512 + sg * 8];
        wq2[it] = *(const ushort8v*)&WoT[(size_t)(n0 + r) * 512 + sg * 8];
    }

    for (int kc = 0; kc < 512; kc += 32) {
        __syncthreads();
#pragma unroll
        for (int it = 0; it < 2; ++it) {
            int r = sr + it * 64;
            *(ushort8v*)&Xl[r * 40 + sg * 8] = xq[it];
            *(ushort8v*)&Wl[r * 40 + sg * 8] = wq2[it];
        }
        __syncthreads();
        if (kc + 32 < 512) {
#pragma unroll
            for (int it = 0; it < 2; ++it) {
                int r = sr + it * 64;
                xq[it]  = *(const ushort8v*)&Zb[(size_t)(m0 + r) * 512 + kc + 32 + sg * 8];
                wq2[it] = *(const ushort8v*)&WoT[(size_t)(n0 + r) * 512 + kc + 32 + sg * 8];
            }
        }
        __builtin_amdgcn_s_setprio(1);
        bf16x8 am[4], an[4];
#pragma unroll
        for (int i = 0; i < 4; ++i)
            am[i] = *(bf16x8*)&Xl[(wm * 64 + i * 16 + ln) * 40 + quad * 8];
#pragma unroll
        for (int j = 0; j < 4; ++j)
            an[j] = *(bf16x8*)&Wl[(wn * 64 + j * 16 + ln) * 40 + quad * 8];
#pragma unroll
        for (int i = 0; i < 4; ++i)
#pragma unroll
            for (int j = 0; j < 4; ++j)
                acc[i][j] = MFMA16(an[j], am[i], acc[i][j]);
        __builtin_amdgcn_s_setprio(0);
    }
#pragma unroll
    for (int i = 0; i < 4; ++i) {
        int m = m0 + wm * 64 + i * 16 + ln;
#pragma unroll
        for (int j = 0; j < 4; ++j) {
            int n = n0 + wn * 64 + j * 16 + quad * 4;
            float4 s;
            s.x = acc[i][j][0]; s.y = acc[i][j][1];
            s.z = acc[i][j][2]; s.w = acc[i][j][3];
            *(float4*)&out[(size_t)m * 512 + n] = s;
        }
    }
}

// ---------------------------------------------------------------- launch
extern "C" void kernel_launch(void* const* d_in, const int* in_sizes, int n_in,
                              void* d_out, int out_size, void* d_ws, size_t ws_size,
                              hipStream_t stream) {
    const float* xs   = (const float*)d_in[0];
    const int*   mask = (const int*)d_in[1];
    const float* Wq   = (const float*)d_in[2];
    const float* Wk   = (const float*)d_in[3];
    const float* Wv   = (const float*)d_in[4];
    const float* Wpos = (const float*)d_in[5];
    const float* Wout = (const float*)d_in[6];
    const float* ub   = (const float*)d_in[7];
    const float* vb   = (const float*)d_in[8];
    float* out = (float*)d_out;

    u16* Qb  = (u16*)d_ws;                   // 4194304
    u16* Kb  = Qb + 4194304;                 // 4194304
    u16* Vtg = Kb + 4194304;                 // 4194304
    u16* Pg  = Vtg + 4194304;                // 8*2048*64 = 1048576
    u16* XZ  = Pg + 1048576;                 // 4194304 (Xb, then reused as Z)
    u16* WT  = XZ + 4194304;                 // 5*262144 = 1310720
    u16* WqT = WT;
    u16* WkT = WT + 262144;
    u16* WvT = WT + 524288;
    u16* WoT = WT + 786432;
    u16* WposT = WT + 1048576;
    u16* Peb = WT + 1310720;                 // 2048*512 = 1048576
    u64* Mp  = (u64*)(Peb + 1048576);        // 131072 u64

    prep_kernel<<<4928, 256, 0, stream>>>(xs, XZ, Wq, Wk, Wv, Wout, Wpos, WT,
                                          mask, Mp, Peb);
    qkv_mfma<<<dim3(64, 13), 256, 0, stream>>>(XZ, WqT, WkT, WvT, Peb, WposT,
                                               Qb, Kb, Vtg, Pg);
    attn_mfma<<<512, 256, 0, stream>>>(Qb, Kb, Vtg, Pg, Mp, ub, vb, XZ);
    out_mfma<<<dim3(64, 4), 256, 0, stream>>>(XZ, WoT, out);
}